// Round 11
// baseline (6796.999 us; speedup 1.0000x reference)
//
#include <hip/hip_runtime.h>

typedef unsigned short u16;
typedef unsigned int u32;
typedef __attribute__((ext_vector_type(8))) short short8v;   // 8 bf16 (4 VGPR) MFMA frag
typedef __attribute__((ext_vector_type(4))) float f32x4;     // MFMA acc
typedef __attribute__((ext_vector_type(8))) u16 ush8;
typedef __attribute__((ext_vector_type(4))) u16 ush4;

__device__ __forceinline__ u16 f2bf(float x) {               // RNE f32->bf16
  u32 u = __builtin_bit_cast(u32, x);
  return (u16)((u + 0x7FFFu + ((u >> 16) & 1u)) >> 16);
}
__device__ __forceinline__ float bf2f(u16 h) {
  u32 u = ((u32)h) << 16;
  return __builtin_bit_cast(float, u);
}
__device__ __forceinline__ float sigm(float x) { return 1.f / (1.f + expf(-x)); }

typedef const __attribute__((address_space(1))) void gv_t;
typedef __attribute__((address_space(3))) void lv_t;
__device__ __forceinline__ void gload16(const void* g, void* l) {
  __builtin_amdgcn_global_load_lds((gv_t*)g, (lv_t*)l, 16, 0, 0);
}

// --- device-coherent access helpers -----------------------------------------
__device__ __forceinline__ u32 ldsc32(const u32* p) {        // bypass L1/L2
  u32 v;
  asm volatile("global_load_dword %0, %1, off sc0 sc1\n\ts_waitcnt vmcnt(0)"
               : "=v"(v) : "v"(p) : "memory");
  return v;
}
// MALL coherent store: device-scope atomic swap, NO-RETURN form
__device__ __forceinline__ void atomswap32(u32* p, u32 v) {
  asm volatile("global_atomic_swap %0, %1, off" :: "v"(p), "v"(v) : "memory");
}

// ---------------------------------------------------------------------------
// ConvLSTM recurrence: one WG per (b, row). Computes h for all t, stores
// split-bf16 h_vec rows [t*16+b][4096].  d = r*256 + ch*16 + col.
// ---------------------------------------------------------------------------
__global__ __launch_bounds__(256) void k_conv(int cin, int xmode,
    const float* __restrict__ xin, const float* __restrict__ cw,
    const float* __restrict__ cb, u16* __restrict__ hhi, u16* __restrict__ hlo)
{
  __shared__ float zb[32 * 18];        // cin x (16+2 pad)
  __shared__ float wb[64 * 32 * 3];
  __shared__ float bb[64];
  const int tid = threadIdx.x;
  const int b = blockIdx.x >> 4, r = blockIdx.x & 15;
  const int ch = tid >> 4, col = tid & 15;
  const int cx = cin - 16;
  for (int i = tid; i < 64 * cin * 3; i += 256) wb[i] = cw[i];
  if (tid < 64) bb[tid] = cb[tid];
  for (int i = tid; i < cin * 18; i += 256) zb[i] = 0.f;  // includes pad cols
  __syncthreads();
  float h = 0.f, c = 0.f;
  for (int t = 0; t < 128; ++t) {
    if (xmode == 0) {
      if (ch == 0) zb[col + 1] = xin[((long)b * 128 + t) * 256 + r * 16 + col];
    } else {
      zb[ch * 18 + col + 1] = xin[((long)t * 16 + b) * 4096 + r * 256 + ch * 16 + col];
    }
    zb[(cx + ch) * 18 + col + 1] = h;
    __syncthreads();
    float a0 = bb[ch], a1 = bb[16 + ch], a2 = bb[32 + ch], a3 = bb[48 + ch];
    for (int ic = 0; ic < cin; ++ic) {
      float z0 = zb[ic * 18 + col], z1 = zb[ic * 18 + col + 1], z2 = zb[ic * 18 + col + 2];
      const float* w0 = &wb[((0 * 16 + ch) * cin + ic) * 3];
      const float* w1 = &wb[((1 * 16 + ch) * cin + ic) * 3];
      const float* w2 = &wb[((2 * 16 + ch) * cin + ic) * 3];
      const float* w3 = &wb[((3 * 16 + ch) * cin + ic) * 3];
      a0 += z0 * w0[0] + z1 * w0[1] + z2 * w0[2];
      a1 += z0 * w1[0] + z1 * w1[1] + z2 * w1[2];
      a2 += z0 * w2[0] + z1 * w2[1] + z2 * w2[2];
      a3 += z0 * w3[0] + z1 * w3[1] + z2 * w3[2];
    }
    __syncthreads();
    c = sigm(a1) * c + sigm(a0) * tanhf(a2);   // i,f,g,o gate order
    h = sigm(a3) * tanhf(c);
    long idx = ((long)t * 16 + b) * 4096 + (long)r * 256 + ch * 16 + col;
    u16 hh = f2bf(h);
    hhi[idx] = hh;
    hlo[idx] = f2bf(h - bf2f(hh));
  }
}

// ---------------------------------------------------------------------------
// Transpose + split: W[4096][4096] fp32 (row k, col n) -> WT_hi/lo[n][k] bf16
// ---------------------------------------------------------------------------
__global__ __launch_bounds__(256) void k_tsplit(const float* __restrict__ W,
    u16* __restrict__ hi, u16* __restrict__ lo)
{
  __shared__ float tb[32][33];
  const int tn = blockIdx.x & 127, tk = blockIdx.x >> 7;
  const int n0 = tn * 32, k0 = tk * 32;
  const int lr = threadIdx.x >> 5, lc = threadIdx.x & 31;
  #pragma unroll
  for (int i = 0; i < 4; ++i)
    tb[lr + i * 8][lc] = W[(long)(k0 + lr + i * 8) * 4096 + n0 + lc];
  __syncthreads();
  #pragma unroll
  for (int i = 0; i < 4; ++i) {
    int n = lr + i * 8;
    float v = tb[lc][n];
    long idx = (long)(n0 + n) * 4096 + k0 + lc;
    u16 h = f2bf(v);
    hi[idx] = h;
    lo[idx] = f2bf(v - bf2f(h));
  }
}

// Elementwise split (no transpose) for wv
__global__ __launch_bounds__(256) void k_split(const float* __restrict__ W,
    u16* __restrict__ hi, u16* __restrict__ lo)
{
  long i = ((long)blockIdx.x * 256 + threadIdx.x) * 4;
  const float4 v = *(const float4*)&W[i];
  u16 h0 = f2bf(v.x), h1 = f2bf(v.y), h2 = f2bf(v.z), h3 = f2bf(v.w);
  ush4 hv = {h0, h1, h2, h3};
  ush4 lv = {f2bf(v.x - bf2f(h0)), f2bf(v.y - bf2f(h1)),
             f2bf(v.z - bf2f(h2)), f2bf(v.w - bf2f(h3))};
  *(ush4*)&hi[i] = hv;
  *(ush4*)&lo[i] = lv;
}

// ---------------------------------------------------------------------------
// OLD split-bf16 GEMM (2-phase dbuf) — kept for the batched scores GEMM.
// ---------------------------------------------------------------------------
__global__ __launch_bounds__(256) void k_gemm(
    const u16* __restrict__ Ahi, const u16* __restrict__ Alo, long lda, long aBS,
    const u16* __restrict__ Bhi, const u16* __restrict__ Blo, long ldb, long bBS,
    float* __restrict__ Cf, u16* __restrict__ Chi, u16* __restrict__ Clo,
    long ldc, long cBS, int nTc, int mode)
{
  __shared__ __align__(16) u16 lds[2][16384];   // per buf: PA @0, PB @8192
  const int tid = threadIdx.x;
  const int lane = tid & 63;
  const int wv = tid >> 6;
  const int bx = blockIdx.x;
  const int nT = bx % nTc;
  const int mT = bx / nTc;
  const long aOff = (long)blockIdx.y * aBS;
  const long bOff = (long)blockIdx.y * bBS;
  const long cOff = (long)blockIdx.y * cBS;
  const long aRow0 = (long)mT * 128;
  const long bRow0 = (long)nT * 128;

  const int l8 = lane >> 3;             // row-within-8 AND swizzle key
  const int cslot = (lane & 7) ^ l8;    // logical chunk this lane fetches
  const int ck = (cslot & 3) * 8;
  const u16* aSrc = ((cslot < 4) ? Ahi : Alo) + aOff + (aRow0 + wv * 32 + l8) * lda + ck;
  const u16* bSrc = ((cslot < 4) ? Bhi : Blo) + bOff + (bRow0 + wv * 32 + l8) * ldb + ck;
  const int ldsAo = wv * 2048;          // wave wv stages rows wv*32..+31
  const int ldsBo = 8192 + wv * 2048;

  const int r15 = lane & 15, kq = lane >> 4;
  const int s7 = r15 & 7;
  const int oHi = (kq ^ s7) * 8;        // swizzled u16 offset of hi chunk
  const int oLo = ((4 + kq) ^ s7) * 8;  // swizzled u16 offset of lo chunk
  const int aQ = (wv >> 1) * 64;        // waveM*64
  const int bQ = (wv & 1) * 64;         // waveN*64

  f32x4 acc[4][4] = {};

#define STAGE(buf, kofs)                                                     \
  {                                                                          \
    const u16* sa = aSrc + (kofs);                                           \
    const u16* sb = bSrc + (kofs);                                           \
    u16* la = &lds[buf][ldsAo];                                              \
    u16* lb = &lds[buf][ldsBo];                                              \
    gload16(sa,            la);        gload16(sa +  8 * lda, la + 512);     \
    gload16(sa + 16 * lda, la + 1024); gload16(sa + 24 * lda, la + 1536);    \
    gload16(sb,            lb);        gload16(sb +  8 * ldb, lb + 512);     \
    gload16(sb + 16 * ldb, lb + 1024); gload16(sb + 24 * ldb, lb + 1536);    \
  }

  STAGE(0, 0)
  __syncthreads();                      // vmcnt(0) drained: buf0 ready
  int cur = 0;
  for (int k0 = 0; k0 < 4096; k0 += 32) {
    if (k0 + 32 < 4096) STAGE(cur ^ 1, k0 + 32)   // flies during MFMA phase
    const u16* L = &lds[cur][0];
    short8v bh[4], bl[4];
    #pragma unroll
    for (int j = 0; j < 4; ++j) {
      int rb = 8192 + (bQ + j * 16 + r15) * 64;
      bh[j] = *(const short8v*)&L[rb + oHi];
      bl[j] = *(const short8v*)&L[rb + oLo];
    }
    #pragma unroll
    for (int i = 0; i < 4; ++i) {
      int ra = (aQ + i * 16 + r15) * 64;
      short8v ah = *(const short8v*)&L[ra + oHi];
      short8v al = *(const short8v*)&L[ra + oLo];
      #pragma unroll
      for (int j = 0; j < 4; ++j) {
        acc[i][j] = __builtin_amdgcn_mfma_f32_16x16x32_bf16(ah, bh[j], acc[i][j], 0, 0, 0);
        acc[i][j] = __builtin_amdgcn_mfma_f32_16x16x32_bf16(ah, bl[j], acc[i][j], 0, 0, 0);
        acc[i][j] = __builtin_amdgcn_mfma_f32_16x16x32_bf16(al, bh[j], acc[i][j], 0, 0, 0);
      }
    }
    __syncthreads();   // next buf staged + all reads of cur done
    cur ^= 1;
  }
#undef STAGE
  const long row0 = aRow0 + aQ;
  const long col0 = bRow0 + bQ;
  #pragma unroll
  for (int i = 0; i < 4; ++i)
    #pragma unroll
    for (int j = 0; j < 4; ++j) {
      long rr = row0 + i * 16 + kq * 4;
      long cc = col0 + j * 16 + r15;
      #pragma unroll
      for (int g = 0; g < 4; ++g) {
        float v = acc[i][j][g];
        long idx = cOff + (rr + g) * ldc + cc;
        if (mode == 0) {
          Cf[idx] = v;
        } else {
          u16 h = f2bf(v);
          Chi[idx] = h;
          Clo[idx] = f2bf(v - bf2f(h));
        }
      }
    }
}

// ---------------------------------------------------------------------------
// 256x128-tile split-bf16 GEMM. 8 waves (4m x 2n), wave C = 64x64.
// 3-buffer LDS rotation (144 KB), ONE barrier/tile, counted vmcnt(6):
// loads stay 2 tiles in flight; ds_reads+MFMAs compiler-interleaved.
// Grid = (M/256)*(N/128), must be divisible by 8 (XCD swizzle).
// ---------------------------------------------------------------------------
__global__ __launch_bounds__(512) void k_gemm256(
    const u16* __restrict__ Ahi, const u16* __restrict__ Alo,
    const u16* __restrict__ Bhi, const u16* __restrict__ Blo,
    u16* __restrict__ Chi, u16* __restrict__ Clo, long ldc, int nTc)
{
  __shared__ __align__(16) u16 lds[73728];   // 3 bufs x (A 16384 | B 8192)
  const int tid = threadIdx.x, lane = tid & 63, wv = tid >> 6;
  const int nwg = gridDim.x;
  const int bid2 = (blockIdx.x & 7) * (nwg >> 3) + (blockIdx.x >> 3);
  const int nT = bid2 % nTc, mT = bid2 / nTc;
  const long aRow0 = (long)mT * 256, bRow0 = (long)nT * 128;

  const int l8 = lane >> 3, cslot = (lane & 7) ^ l8, ck = (cslot & 3) * 8;
  const u16* aSrc = ((cslot < 4) ? Ahi : Alo) + (aRow0 + wv * 32 + l8) * 4096 + ck;
  const u16* bSrc = ((cslot < 4) ? Bhi : Blo) + (bRow0 + wv * 16 + l8) * 4096 + ck;
  const int laO = wv * 2048;            // A: wave stages 32 rows x 64 u16
  const int lbO = 16384 + wv * 1024;    // B: wave stages 16 rows x 64 u16

  const int r15 = lane & 15, kq = lane >> 4, s7 = r15 & 7;
  const int oHi = (kq ^ s7) * 8, oLo = ((4 + kq) ^ s7) * 8;
  const int wm = wv >> 1, wn = wv & 1;
  f32x4 acc[4][4] = {};

#define STG(buf, kofs)                                                       \
  {                                                                          \
    const u16* sa = aSrc + (kofs);                                           \
    const u16* sb = bSrc + (kofs);                                           \
    u16* la = &lds[(buf) * 24576 + laO];                                     \
    u16* lb = &lds[(buf) * 24576 + lbO];                                     \
    gload16(sa,             la);       gload16(sa +  8 * 4096, la + 512);    \
    gload16(sa + 16 * 4096, la + 1024); gload16(sa + 24 * 4096, la + 1536);  \
    gload16(sb,             lb);       gload16(sb +  8 * 4096, lb + 512);    \
  }

  STG(0, 0) STG(1, 32)                  // tiles 0,1 in flight (12 loads)
  for (int kt = 0; kt < 128; ++kt) {
    if (kt < 127) { asm volatile("s_waitcnt vmcnt(6)" ::: "memory"); }
    else          { asm volatile("s_waitcnt vmcnt(0)" ::: "memory"); }
    __builtin_amdgcn_sched_barrier(0);
    __builtin_amdgcn_s_barrier();       // all waves' tile-kt loads complete
    const int bb = (kt % 3) * 24576;
    if (kt < 126) STG((kt + 2) % 3, (kt + 2) * 32)   // 2-deep prefetch
    short8v ah[4], al[4], bh[4], bl[4];
    #pragma unroll
    for (int j = 0; j < 4; ++j) {
      int rb = bb + 16384 + (wn * 64 + j * 16 + r15) * 64;
      bh[j] = *(const short8v*)&lds[rb + oHi];
      bl[j] = *(const short8v*)&lds[rb + oLo];
    }
    #pragma unroll
    for (int i = 0; i < 4; ++i) {
      int ra = bb + (wm * 64 + i * 16 + r15) * 64;
      ah[i] = *(const short8v*)&lds[ra + oHi];
      al[i] = *(const short8v*)&lds[ra + oLo];
    }
    #pragma unroll
    for (int i = 0; i < 4; ++i)
      #pragma unroll
      for (int j = 0; j < 4; ++j) {
        acc[i][j] = __builtin_amdgcn_mfma_f32_16x16x32_bf16(ah[i], bh[j], acc[i][j], 0, 0, 0);
        acc[i][j] = __builtin_amdgcn_mfma_f32_16x16x32_bf16(ah[i], bl[j], acc[i][j], 0, 0, 0);
        acc[i][j] = __builtin_amdgcn_mfma_f32_16x16x32_bf16(al[i], bh[j], acc[i][j], 0, 0, 0);
      }
  }
#undef STG
  // epilogue: split-bf16 store (m89 layout)
  const long row0 = aRow0 + wm * 64;
  const long col0 = bRow0 + wn * 64;
  #pragma unroll
  for (int i = 0; i < 4; ++i)
    #pragma unroll
    for (int j = 0; j < 4; ++j) {
      long rr = row0 + i * 16 + kq * 4;
      long cc = col0 + j * 16 + r15;
      #pragma unroll
      for (int g = 0; g < 4; ++g) {
        float v = acc[i][j][g];
        long idx = (rr + g) * ldc + cc;
        u16 h = f2bf(v);
        Chi[idx] = h;
        Clo[idx] = f2bf(v - bf2f(h));
      }
    }
}

// Softmax over strictly-past scores -> Wx[t][b][t']; also zeroes the barrier
// arrival/release lines via MALL atomics.
__global__ __launch_bounds__(256) void k_softmax(const float* __restrict__ S,
    float* __restrict__ Wx, u32* __restrict__ flags, u32* __restrict__ rel)
{
  if (blockIdx.x == 0) atomswap32(&flags[threadIdx.x * 16], 0);
  if (blockIdx.x == 1) atomswap32(&rel[threadIdx.x * 16], 0);
  const int wv = threadIdx.x >> 6, lane = threadIdx.x & 63;
  const int idx = blockIdx.x * 4 + wv;        // = b*128 + t
  const int b = idx >> 7, t = idx & 127;
  const float* row = &S[(long)idx * 128];
  float v0 = (lane < t) ? row[lane] * 0.015625f : -1e30f;
  float v1 = (lane + 64 < t) ? row[lane + 64] * 0.015625f : -1e30f;
  float m = fmaxf(v0, v1);
  #pragma unroll
  for (int off = 32; off; off >>= 1) m = fmaxf(m, __shfl_xor(m, off));
  float e0 = (lane < t) ? expf(v0 - m) : 0.f;
  float e1 = (lane + 64 < t) ? expf(v1 - m) : 0.f;
  float s = e0 + e1;
  #pragma unroll
  for (int off = 32; off; off >>= 1) s += __shfl_xor(s, off);
  float inv = 1.f / fmaxf(s, 1e-9f);
  float* wr = &Wx[((long)t * 16 + b) * 128];
  wr[lane] = e0 * inv;
  wr[lane + 64] = e1 * inv;
}

// ---------------------------------------------------------------------------
// Persistent phase C (unchanged from r9/r10). grid 256, 512 thr = 8 waves.
// ---------------------------------------------------------------------------
__global__ __launch_bounds__(512) void k_phaseC(
    const u16* __restrict__ Wvh, const u16* __restrict__ Wvl,
    const float* __restrict__ Wx,
    const u16* __restrict__ hoh, const u16* __restrict__ hol,
    u16* __restrict__ ring_h, u16* __restrict__ ring_l,
    float* __restrict__ fdest, int dmode,
    u32* __restrict__ flags, u32* __restrict__ rel)
{
  __shared__ float VO_lds[128 * 256];        // [t][b*16+col]  128 KB
  __shared__ float vo_w[8][256];
  __shared__ float pctx[2][256];
  const int tid = threadIdx.x;
  const int lane = tid & 63, wv = tid >> 6;
  const int n0 = blockIdx.x * 16;
  const int r15 = lane & 15, kq = lane >> 4;
  const long kb = (long)wv * 512 + kq * 8;   // this lane's K base

  short8v Bh[16], Bl[16];
  {
    const u16* bh = Wvh + (long)(n0 + r15) * 4096 + kb;
    const u16* bl = Wvl + (long)(n0 + r15) * 4096 + kb;
    #pragma unroll
    for (int c = 0; c < 16; ++c) {
      Bh[c] = *(const short8v*)(bh + c * 32);
      Bl[c] = *(const short8v*)(bl + c * 32);
    }
    #pragma unroll
    for (int c = 0; c < 16; ++c) {
      asm volatile("" : "+v"(Bh[c]));
      asm volatile("" : "+v"(Bl[c]));
    }
  }
  const long abase = (long)r15 * 4096 + kb;  // A-frag base (row = batch r15)
  const int b8 = tid >> 4, col8 = tid & 15;  // (b, col) for tid<256

#define GBAR(n)                                                              \
  {                                                                          \
    asm volatile("s_waitcnt vmcnt(0)" ::: "memory");                         \
    __syncthreads();                                                         \
    if (tid == 0) {                                                          \
      atomswap32(&flags[(u32)blockIdx.x * 16], (n));                         \
      asm volatile("s_waitcnt vmcnt(0)" ::: "memory");                       \
    }                                                                        \
    if (blockIdx.x == 0) {                                                   \
      if (tid < 256) {                                                       \
        while (ldsc32(&flags[tid * 16]) < (n)) __builtin_amdgcn_s_sleep(1);  \
      }                                                                      \
      __syncthreads();                                                       \
      if (tid < 256) atomswap32(&rel[tid * 16], (n));                        \
    } else if (tid == 0) {                                                   \
      while (ldsc32(&rel[(u32)blockIdx.x * 16]) < (n))                       \
        __builtin_amdgcn_s_sleep(1);                                         \
    }                                                                        \
    __syncthreads();                                                         \
  }

#define RING_STORE(slot, oval)                                               \
  {                                                                          \
    u16 hh_ = f2bf(oval);                                                    \
    u16 hl_ = f2bf((oval)-bf2f(hh_));                                        \
    u32 vh_ = hh_, vl_ = hl_;                                                \
    u32 ph_ = (u32)__shfl_xor((int)vh_, 1);                                  \
    u32 pl_ = (u32)__shfl_xor((int)vl_, 1);                                  \
    if (!(col8 & 1)) {                                                       \
      long oi_ = (long)(slot) * 65536 + (long)b8 * 4096 + n0 + col8;         \
      atomswap32((u32*)&ring_h[oi_], vh_ | (ph_ << 16));                     \
      atomswap32((u32*)&ring_l[oi_], vl_ | (pl_ << 16));                     \
    }                                                                        \
  }

  if (tid < 256) {
    float v = tanhf(bf2f(hoh[(long)b8 * 12288 + n0 + col8])
                  + bf2f(hol[(long)b8 * 12288 + n0 + col8]));
    RING_STORE(0, v)
    if (dmode == 0) fdest[(long)b8 * 4096 + n0 + col8] = v;
    else            fdest[(long)b8 * 128 * 4096 + n0 + col8] = v;
  }
  u32 bn = 1;
  GBAR(bn) ++bn;

#define MF(a, b) acc = __builtin_amdgcn_mfma_f32_16x16x32_bf16(a, b, acc, 0, 0, 0);

  for (int t = 0; t < 127; ++t) {
    const u16* ph = ring_h + (long)t * 65536 + abase;   // plain cached loads
    const u16* pl = ring_l + (long)t * 65536 + abase;
    f32x4 acc = {0.f, 0.f, 0.f, 0.f};
    {
      short8v xh[8], xl[8];
      #pragma unroll
      for (int c = 0; c < 8; ++c) {
        xh[c] = *(const short8v*)(ph + c * 32);
        xl[c] = *(const short8v*)(pl + c * 32);
      }
      #pragma unroll
      for (int c = 0; c < 8; ++c) { MF(xh[c], Bh[c]) MF(xh[c], Bl[c]) MF(xl[c], Bh[c]) }
    }
    {
      short8v xh[8], xl[8];
      #pragma unroll
      for (int c = 0; c < 8; ++c) {
        xh[c] = *(const short8v*)(ph + 256 + c * 32);
        xl[c] = *(const short8v*)(pl + 256 + c * 32);
      }
      #pragma unroll
      for (int c = 0; c < 8; ++c) { MF(xh[c], Bh[8 + c]) MF(xh[c], Bl[8 + c]) MF(xl[c], Bh[8 + c]) }
    }

    #pragma unroll
    for (int g = 0; g < 4; ++g)
      vo_w[wv][(kq * 4 + g) * 16 + r15] = acc[g];
    __syncthreads();
    float v = 0.f;
    if (tid < 256) {
      v = vo_w[0][tid] + vo_w[1][tid] + vo_w[2][tid] + vo_w[3][tid]
        + vo_w[4][tid] + vo_w[5][tid] + vo_w[6][tid] + vo_w[7][tid];
      VO_lds[t * 256 + tid] = v;
    }
    {
      const int p = tid >> 8, id = tid & 255;
      const int b = id >> 4;
      const float* wrow = &Wx[((long)(t + 1) * 16 + b) * 128];
      float ctx = 0.f;
      for (int tp = p; tp < t; tp += 2)
        ctx += wrow[tp] * VO_lds[tp * 256 + id];
      pctx[p][id] = ctx;
    }
    __syncthreads();
    if (tid < 256) {
      const float* wrow = &Wx[((long)(t + 1) * 16 + b8) * 128];
      long hix = ((long)(t + 1) * 16 + b8) * 12288 + n0 + col8;
      float o = tanhf(bf2f(hoh[hix]) + bf2f(hol[hix])
                      + pctx[0][tid] + pctx[1][tid] + wrow[t] * v);
      RING_STORE(t + 1, o)
      if (dmode == 0) fdest[((long)(t + 1) * 16 + b8) * 4096 + n0 + col8] = o;
      else            fdest[((long)b8 * 128 + (t + 1)) * 4096 + n0 + col8] = o;
    }
    if (t < 126) { GBAR(bn) ++bn; }
  }
#undef GBAR
#undef RING_STORE
#undef MF
}

// ---------------------------------------------------------------------------
extern "C" void kernel_launch(void* const* d_in, const int* in_sizes, int n_in,
                              void* d_out, int out_size, void* d_ws, size_t ws_size,
                              hipStream_t stream)
{
  (void)in_sizes; (void)n_in; (void)out_size;
  if (ws_size < 472383488UL) return;  // need ~451 MiB scratch
  char* ws = (char*)d_ws;
  u16* WT_hi = (u16*)(ws + 0UL);               // 96 MB
  u16* WT_lo = (u16*)(ws + 100663296UL);       // 96 MB
  u16* WV_hi = (u16*)(ws + 33554432UL);        // reuses dead WT rows
  u16* WV_lo = (u16*)(ws + 134217728UL);
  u16* QKOh  = (u16*)(ws + 201326592UL);       // [2048][12288] hi (48 MB)
  u16* QKOl  = (u16*)(ws + 251658240UL);       // lo (48 MB)
  u16* Wvo_hi = (u16*)(ws + 301989888UL);      // 32 MB (reused per layer)
  u16* Wvo_lo = (u16*)(ws + 335544320UL);      // 32 MB
  u16* Hs_hi = (u16*)(ws + 369098752UL);       // 16 MB
  u16* Hs_lo = (u16*)(ws + 385875968UL);
  float* Sb   = (float*)(ws + 402653184UL);    // 1 MB
  float* Wmx  = (float*)(ws + 403701760UL);    // 1 MB
  float* OUT0 = (float*)(ws + 404754432UL);    // 32 MB
  u16* ring_h = (u16*)(ws + 438308864UL);      // 16 MB: 128 x [16][4096]
  u16* ring_l = (u16*)(ws + 455086080UL);      // 16 MB
  u32* flg    = (u32*)(ws + 471859200UL);      // 16 KB (256 x 64B lines)
  u32* rel    = (u32*)(ws + 471875584UL);      // 16 KB (256 x 64B lines)
  float* dout = (float*)d_out;
  const float* x_flat = (const float*)d_in[0];

  for (int l = 0; l < 2; ++l) {
    const float* cw = (const float*)d_in[1 + l * 6];
    const float* cb = (const float*)d_in[2 + l * 6];
    const float* wq = (const float*)d_in[3 + l * 6];
    const float* wk = (const float*)d_in[4 + l * 6];
    const float* wv = (const float*)d_in[5 + l * 6];
    const float* wo = (const float*)d_in[6 + l * 6];
    const int cin = (l == 0) ? 17 : 32;

    // Phase A: ConvLSTM recurrence -> split h_vec rows
    hipLaunchKernelGGL(k_conv, dim3(256), dim3(256), 0, stream,
        cin, l, (l == 0) ? x_flat : OUT0, cw, cb, Hs_hi, Hs_lo);

    // Phase B1: stack wq^T | wk^T | wo_h^T into WT, then ONE fused GEMM
    hipLaunchKernelGGL(k_tsplit, dim3(16384), dim3(256), 0, stream,
        wq, WT_hi, WT_lo);
    hipLaunchKernelGGL(k_tsplit, dim3(16384), dim3(256), 0, stream,
        wk, WT_hi + 16777216UL, WT_lo + 16777216UL);
    hipLaunchKernelGGL(k_tsplit, dim3(16384), dim3(256), 0, stream,
        wo, WT_hi + 33554432UL, WT_lo + 33554432UL);
    hipLaunchKernelGGL(k_gemm256, dim3(768), dim3(512), 0, stream,
        Hs_hi, Hs_lo, WT_hi, WT_lo, QKOh, QKOl, 12288L, 96);

    // Phase B2: composite Wvo^T = (wv @ wo_c)^T
    hipLaunchKernelGGL(k_tsplit, dim3(16384), dim3(256), 0, stream,
        wo + 16777216UL, WT_hi, WT_lo);                       // wo_c^T
    hipLaunchKernelGGL(k_split, dim3(16384), dim3(256), 0, stream, wv, WV_hi, WV_lo);
    hipLaunchKernelGGL(k_gemm256, dim3(512), dim3(512), 0, stream,
        WT_hi, WT_lo, WV_hi, WV_lo, Wvo_hi, Wvo_lo, 4096L, 32);

    // Scores via batched MFMA GEMM: S[b][t][t'] = Q[t,b,:]·K[t',b,:]
    hipLaunchKernelGGL(k_gemm, dim3(1, 16), dim3(256), 0, stream,
        QKOh, QKOl, 196608L, 12288L, QKOh + 4096, QKOl + 4096, 196608L, 12288L,
        Sb, (u16*)nullptr, (u16*)nullptr, 128L, 16384L, 1, 0);
    hipLaunchKernelGGL(k_softmax, dim3(512), dim3(256), 0, stream, Sb, Wmx, flg, rel);

    // Phase C: ONE persistent kernel (MALL-resident ring + barrier)
    hipLaunchKernelGGL(k_phaseC, dim3(256), dim3(512), 0, stream,
        Wvo_hi, Wvo_lo, Wmx, QKOh + 8192, QKOl + 8192,
        ring_h, ring_l, (l == 0) ? OUT0 : dout, l, flg, rel);
  }
}

// Round 12
// 4990.038 us; speedup vs baseline: 1.3621x; 1.3621x over previous
//
#include <hip/hip_runtime.h>

typedef unsigned short u16;
typedef unsigned int u32;
typedef __attribute__((ext_vector_type(8))) short short8v;   // 8 bf16 (4 VGPR) MFMA frag
typedef __attribute__((ext_vector_type(4))) float f32x4;     // MFMA acc
typedef __attribute__((ext_vector_type(8))) u16 ush8;
typedef __attribute__((ext_vector_type(4))) u16 ush4;

__device__ __forceinline__ u16 f2bf(float x) {               // RNE f32->bf16
  u32 u = __builtin_bit_cast(u32, x);
  return (u16)((u + 0x7FFFu + ((u >> 16) & 1u)) >> 16);
}
__device__ __forceinline__ float bf2f(u16 h) {
  u32 u = ((u32)h) << 16;
  return __builtin_bit_cast(float, u);
}
__device__ __forceinline__ float sigm(float x) { return 1.f / (1.f + expf(-x)); }

typedef const __attribute__((address_space(1))) void gv_t;
typedef __attribute__((address_space(3))) void lv_t;
__device__ __forceinline__ void gload16(const void* g, void* l) {
  __builtin_amdgcn_global_load_lds((gv_t*)g, (lv_t*)l, 16, 0, 0);
}

// --- device-coherent access helpers -----------------------------------------
__device__ __forceinline__ u32 ldsc32(const u32* p) {        // bypass L1/L2
  u32 v;
  asm volatile("global_load_dword %0, %1, off sc0 sc1\n\ts_waitcnt vmcnt(0)"
               : "=v"(v) : "v"(p) : "memory");
  return v;
}
// MALL coherent store: device-scope atomic swap, NO-RETURN form
__device__ __forceinline__ void atomswap32(u32* p, u32 v) {
  asm volatile("global_atomic_swap %0, %1, off" :: "v"(p), "v"(v) : "memory");
}

// ---------------------------------------------------------------------------
// ConvLSTM recurrence: one WG per (b, row). Computes h for all t, stores
// split-bf16 h_vec rows [t*16+b][4096].  d = r*256 + ch*16 + col.
// ---------------------------------------------------------------------------
__global__ __launch_bounds__(256) void k_conv(int cin, int xmode,
    const float* __restrict__ xin, const float* __restrict__ cw,
    const float* __restrict__ cb, u16* __restrict__ hhi, u16* __restrict__ hlo)
{
  __shared__ float zb[32 * 18];        // cin x (16+2 pad)
  __shared__ float wb[64 * 32 * 3];
  __shared__ float bb[64];
  const int tid = threadIdx.x;
  const int b = blockIdx.x >> 4, r = blockIdx.x & 15;
  const int ch = tid >> 4, col = tid & 15;
  const int cx = cin - 16;
  for (int i = tid; i < 64 * cin * 3; i += 256) wb[i] = cw[i];
  if (tid < 64) bb[tid] = cb[tid];
  for (int i = tid; i < cin * 18; i += 256) zb[i] = 0.f;  // includes pad cols
  __syncthreads();
  float h = 0.f, c = 0.f;
  for (int t = 0; t < 128; ++t) {
    if (xmode == 0) {
      if (ch == 0) zb[col + 1] = xin[((long)b * 128 + t) * 256 + r * 16 + col];
    } else {
      zb[ch * 18 + col + 1] = xin[((long)t * 16 + b) * 4096 + r * 256 + ch * 16 + col];
    }
    zb[(cx + ch) * 18 + col + 1] = h;
    __syncthreads();
    float a0 = bb[ch], a1 = bb[16 + ch], a2 = bb[32 + ch], a3 = bb[48 + ch];
    for (int ic = 0; ic < cin; ++ic) {
      float z0 = zb[ic * 18 + col], z1 = zb[ic * 18 + col + 1], z2 = zb[ic * 18 + col + 2];
      const float* w0 = &wb[((0 * 16 + ch) * cin + ic) * 3];
      const float* w1 = &wb[((1 * 16 + ch) * cin + ic) * 3];
      const float* w2 = &wb[((2 * 16 + ch) * cin + ic) * 3];
      const float* w3 = &wb[((3 * 16 + ch) * cin + ic) * 3];
      a0 += z0 * w0[0] + z1 * w0[1] + z2 * w0[2];
      a1 += z0 * w1[0] + z1 * w1[1] + z2 * w1[2];
      a2 += z0 * w2[0] + z1 * w2[1] + z2 * w2[2];
      a3 += z0 * w3[0] + z1 * w3[1] + z2 * w3[2];
    }
    __syncthreads();
    c = sigm(a1) * c + sigm(a0) * tanhf(a2);   // i,f,g,o gate order
    h = sigm(a3) * tanhf(c);
    long idx = ((long)t * 16 + b) * 4096 + (long)r * 256 + ch * 16 + col;
    u16 hh = f2bf(h);
    hhi[idx] = hh;
    hlo[idx] = f2bf(h - bf2f(hh));
  }
}

// ---------------------------------------------------------------------------
// Transpose + split: W[4096][4096] fp32 (row k, col n) -> WT_hi/lo[n][k] bf16
// ---------------------------------------------------------------------------
__global__ __launch_bounds__(256) void k_tsplit(const float* __restrict__ W,
    u16* __restrict__ hi, u16* __restrict__ lo)
{
  __shared__ float tb[32][33];
  const int tn = blockIdx.x & 127, tk = blockIdx.x >> 7;
  const int n0 = tn * 32, k0 = tk * 32;
  const int lr = threadIdx.x >> 5, lc = threadIdx.x & 31;
  #pragma unroll
  for (int i = 0; i < 4; ++i)
    tb[lr + i * 8][lc] = W[(long)(k0 + lr + i * 8) * 4096 + n0 + lc];
  __syncthreads();
  #pragma unroll
  for (int i = 0; i < 4; ++i) {
    int n = lr + i * 8;
    float v = tb[lc][n];
    long idx = (long)(n0 + n) * 4096 + k0 + lc;
    u16 h = f2bf(v);
    hi[idx] = h;
    lo[idx] = f2bf(v - bf2f(h));
  }
}

// Elementwise split (no transpose) for wv
__global__ __launch_bounds__(256) void k_split(const float* __restrict__ W,
    u16* __restrict__ hi, u16* __restrict__ lo)
{
  long i = ((long)blockIdx.x * 256 + threadIdx.x) * 4;
  const float4 v = *(const float4*)&W[i];
  u16 h0 = f2bf(v.x), h1 = f2bf(v.y), h2 = f2bf(v.z), h3 = f2bf(v.w);
  ush4 hv = {h0, h1, h2, h3};
  ush4 lv = {f2bf(v.x - bf2f(h0)), f2bf(v.y - bf2f(h1)),
             f2bf(v.z - bf2f(h2)), f2bf(v.w - bf2f(h3))};
  *(ush4*)&hi[i] = hv;
  *(ush4*)&lo[i] = lv;
}

// ---------------------------------------------------------------------------
// 128^2-tile GEMM (2-phase dbuf) — used for the batched scores GEMM.
// NM = #MFMAs per frag pair (1: ah*bh; 2:+al*bh; 3:+ah*bl).
// ---------------------------------------------------------------------------
template<int NM>
__global__ __launch_bounds__(256) void k_gemm(
    const u16* __restrict__ Ahi, const u16* __restrict__ Alo, long lda, long aBS,
    const u16* __restrict__ Bhi, const u16* __restrict__ Blo, long ldb, long bBS,
    float* __restrict__ Cf, u16* __restrict__ Chi, u16* __restrict__ Clo,
    long ldc, long cBS, int nTc, int mode)
{
  __shared__ __align__(16) u16 lds[2][16384];   // per buf: PA @0, PB @8192
  const int tid = threadIdx.x;
  const int lane = tid & 63;
  const int wv = tid >> 6;
  const int bx = blockIdx.x;
  const int nT = bx % nTc;
  const int mT = bx / nTc;
  const long aOff = (long)blockIdx.y * aBS;
  const long bOff = (long)blockIdx.y * bBS;
  const long cOff = (long)blockIdx.y * cBS;
  const long aRow0 = (long)mT * 128;
  const long bRow0 = (long)nT * 128;

  const int l8 = lane >> 3;             // row-within-8 AND swizzle key
  const int cslot = (lane & 7) ^ l8;    // logical chunk this lane fetches
  const int ck = (cslot & 3) * 8;
  const u16* aSrc = ((cslot < 4) ? Ahi : Alo) + aOff + (aRow0 + wv * 32 + l8) * lda + ck;
  const u16* bSrc = ((cslot < 4) ? Bhi : Blo) + bOff + (bRow0 + wv * 32 + l8) * ldb + ck;
  const int ldsAo = wv * 2048;          // wave wv stages rows wv*32..+31
  const int ldsBo = 8192 + wv * 2048;

  const int r15 = lane & 15, kq = lane >> 4;
  const int s7 = r15 & 7;
  const int oHi = (kq ^ s7) * 8;        // swizzled u16 offset of hi chunk
  const int oLo = ((4 + kq) ^ s7) * 8;  // swizzled u16 offset of lo chunk
  const int aQ = (wv >> 1) * 64;        // waveM*64
  const int bQ = (wv & 1) * 64;         // waveN*64

  f32x4 acc[4][4] = {};

#define STAGE(buf, kofs)                                                     \
  {                                                                          \
    const u16* sa = aSrc + (kofs);                                           \
    const u16* sb = bSrc + (kofs);                                           \
    u16* la = &lds[buf][ldsAo];                                              \
    u16* lb = &lds[buf][ldsBo];                                              \
    gload16(sa,            la);        gload16(sa +  8 * lda, la + 512);     \
    gload16(sa + 16 * lda, la + 1024); gload16(sa + 24 * lda, la + 1536);    \
    gload16(sb,            lb);        gload16(sb +  8 * ldb, lb + 512);     \
    gload16(sb + 16 * ldb, lb + 1024); gload16(sb + 24 * ldb, lb + 1536);    \
  }

  STAGE(0, 0)
  __syncthreads();                      // vmcnt(0) drained: buf0 ready
  int cur = 0;
  for (int k0 = 0; k0 < 4096; k0 += 32) {
    if (k0 + 32 < 4096) STAGE(cur ^ 1, k0 + 32)   // flies during MFMA phase
    const u16* L = &lds[cur][0];
    short8v bh[4], bl[4];
    #pragma unroll
    for (int j = 0; j < 4; ++j) {
      int rb = 8192 + (bQ + j * 16 + r15) * 64;
      bh[j] = *(const short8v*)&L[rb + oHi];
      if (NM >= 3) bl[j] = *(const short8v*)&L[rb + oLo];
    }
    #pragma unroll
    for (int i = 0; i < 4; ++i) {
      int ra = (aQ + i * 16 + r15) * 64;
      short8v ah = *(const short8v*)&L[ra + oHi];
      short8v al;
      if (NM >= 2) al = *(const short8v*)&L[ra + oLo];
      #pragma unroll
      for (int j = 0; j < 4; ++j) {
        acc[i][j] = __builtin_amdgcn_mfma_f32_16x16x32_bf16(ah, bh[j], acc[i][j], 0, 0, 0);
        if (NM >= 3) acc[i][j] = __builtin_amdgcn_mfma_f32_16x16x32_bf16(ah, bl[j], acc[i][j], 0, 0, 0);
        if (NM >= 2) acc[i][j] = __builtin_amdgcn_mfma_f32_16x16x32_bf16(al, bh[j], acc[i][j], 0, 0, 0);
      }
    }
    __syncthreads();   // next buf staged + all reads of cur done
    cur ^= 1;
  }
#undef STAGE
  const long row0 = aRow0 + aQ;
  const long col0 = bRow0 + bQ;
  #pragma unroll
  for (int i = 0; i < 4; ++i)
    #pragma unroll
    for (int j = 0; j < 4; ++j) {
      long rr = row0 + i * 16 + kq * 4;
      long cc = col0 + j * 16 + r15;
      #pragma unroll
      for (int g = 0; g < 4; ++g) {
        float v = acc[i][j][g];
        long idx = cOff + (rr + g) * ldc + cc;
        if (mode == 0) {
          Cf[idx] = v;
        } else {
          u16 h = f2bf(v);
          Chi[idx] = h;
          Clo[idx] = f2bf(v - bf2f(h));
        }
      }
    }
}

// ---------------------------------------------------------------------------
// 256x128-tile GEMM, 3-buffer LDS rotation, counted vmcnt(6), 1 barrier/tile.
// NM as above; LOOUT: also write split-lo C. Grid divisible by 8.
// ---------------------------------------------------------------------------
template<int NM, bool LOOUT>
__global__ __launch_bounds__(512) void k_gemm256(
    const u16* __restrict__ Ahi, const u16* __restrict__ Alo,
    const u16* __restrict__ Bhi, const u16* __restrict__ Blo,
    u16* __restrict__ Chi, u16* __restrict__ Clo, long ldc, int nTc)
{
  __shared__ __align__(16) u16 lds[73728];   // 3 bufs x (A 16384 | B 8192)
  const int tid = threadIdx.x, lane = tid & 63, wv = tid >> 6;
  const int nwg = gridDim.x;
  const int bid2 = (blockIdx.x & 7) * (nwg >> 3) + (blockIdx.x >> 3);
  const int nT = bid2 % nTc, mT = bid2 / nTc;
  const long aRow0 = (long)mT * 256, bRow0 = (long)nT * 128;

  const int l8 = lane >> 3, cslot = (lane & 7) ^ l8, ck = (cslot & 3) * 8;
  const u16* aSrc = ((cslot < 4) ? Ahi : Alo) + (aRow0 + wv * 32 + l8) * 4096 + ck;
  const u16* bSrc = ((cslot < 4) ? Bhi : Blo) + (bRow0 + wv * 16 + l8) * 4096 + ck;
  const int laO = wv * 2048;            // A: wave stages 32 rows x 64 u16
  const int lbO = 16384 + wv * 1024;    // B: wave stages 16 rows x 64 u16

  const int r15 = lane & 15, kq = lane >> 4, s7 = r15 & 7;
  const int oHi = (kq ^ s7) * 8, oLo = ((4 + kq) ^ s7) * 8;
  const int wm = wv >> 1, wn = wv & 1;
  f32x4 acc[4][4] = {};

#define STG(buf, kofs)                                                       \
  {                                                                          \
    const u16* sa = aSrc + (kofs);                                           \
    const u16* sb = bSrc + (kofs);                                           \
    u16* la = &lds[(buf) * 24576 + laO];                                     \
    u16* lb = &lds[(buf) * 24576 + lbO];                                     \
    gload16(sa,             la);       gload16(sa +  8 * 4096, la + 512);    \
    gload16(sa + 16 * 4096, la + 1024); gload16(sa + 24 * 4096, la + 1536);  \
    gload16(sb,             lb);       gload16(sb +  8 * 4096, lb + 512);    \
  }

  STG(0, 0) STG(1, 32)                  // tiles 0,1 in flight (12 loads)
  for (int kt = 0; kt < 128; ++kt) {
    if (kt < 127) { asm volatile("s_waitcnt vmcnt(6)" ::: "memory"); }
    else          { asm volatile("s_waitcnt vmcnt(0)" ::: "memory"); }
    __builtin_amdgcn_sched_barrier(0);
    __builtin_amdgcn_s_barrier();       // all waves' tile-kt loads complete
    const int bb = (kt % 3) * 24576;
    if (kt < 126) STG((kt + 2) % 3, (kt + 2) * 32)   // 2-deep prefetch
    short8v ah[4], al[4], bh[4], bl[4];
    #pragma unroll
    for (int j = 0; j < 4; ++j) {
      int rb = bb + 16384 + (wn * 64 + j * 16 + r15) * 64;
      bh[j] = *(const short8v*)&lds[rb + oHi];
      if (NM >= 3) bl[j] = *(const short8v*)&lds[rb + oLo];
    }
    #pragma unroll
    for (int i = 0; i < 4; ++i) {
      int ra = bb + (wm * 64 + i * 16 + r15) * 64;
      ah[i] = *(const short8v*)&lds[ra + oHi];
      if (NM >= 2) al[i] = *(const short8v*)&lds[ra + oLo];
    }
    #pragma unroll
    for (int i = 0; i < 4; ++i)
      #pragma unroll
      for (int j = 0; j < 4; ++j) {
        acc[i][j] = __builtin_amdgcn_mfma_f32_16x16x32_bf16(ah[i], bh[j], acc[i][j], 0, 0, 0);
        if (NM >= 3) acc[i][j] = __builtin_amdgcn_mfma_f32_16x16x32_bf16(ah[i], bl[j], acc[i][j], 0, 0, 0);
        if (NM >= 2) acc[i][j] = __builtin_amdgcn_mfma_f32_16x16x32_bf16(al[i], bh[j], acc[i][j], 0, 0, 0);
      }
  }
#undef STG
  // epilogue: split-bf16 store (m89 layout)
  const long row0 = aRow0 + wm * 64;
  const long col0 = bRow0 + wn * 64;
  #pragma unroll
  for (int i = 0; i < 4; ++i)
    #pragma unroll
    for (int j = 0; j < 4; ++j) {
      long rr = row0 + i * 16 + kq * 4;
      long cc = col0 + j * 16 + r15;
      #pragma unroll
      for (int g = 0; g < 4; ++g) {
        float v = acc[i][j][g];
        long idx = (rr + g) * ldc + cc;
        u16 h = f2bf(v);
        Chi[idx] = h;
        if (LOOUT) Clo[idx] = f2bf(v - bf2f(h));
      }
    }
}

// Softmax over strictly-past scores -> Wx[t][b][t']; also zeroes the barrier
// arrival/release lines via MALL atomics.
__global__ __launch_bounds__(256) void k_softmax(const float* __restrict__ S,
    float* __restrict__ Wx, u32* __restrict__ flags, u32* __restrict__ rel)
{
  if (blockIdx.x == 0) atomswap32(&flags[threadIdx.x * 16], 0);
  if (blockIdx.x == 1) atomswap32(&rel[threadIdx.x * 16], 0);
  const int wv = threadIdx.x >> 6, lane = threadIdx.x & 63;
  const int idx = blockIdx.x * 4 + wv;        // = b*128 + t
  const int b = idx >> 7, t = idx & 127;
  const float* row = &S[(long)idx * 128];
  float v0 = (lane < t) ? row[lane] * 0.015625f : -1e30f;
  float v1 = (lane + 64 < t) ? row[lane + 64] * 0.015625f : -1e30f;
  float m = fmaxf(v0, v1);
  #pragma unroll
  for (int off = 32; off; off >>= 1) m = fmaxf(m, __shfl_xor(m, off));
  float e0 = (lane < t) ? expf(v0 - m) : 0.f;
  float e1 = (lane + 64 < t) ? expf(v1 - m) : 0.f;
  float s = e0 + e1;
  #pragma unroll
  for (int off = 32; off; off >>= 1) s += __shfl_xor(s, off);
  float inv = 1.f / fmaxf(s, 1e-9f);
  float* wr = &Wx[((long)t * 16 + b) * 128];
  wr[lane] = e0 * inv;
  wr[lane + 64] = e1 * inv;
}

// ---------------------------------------------------------------------------
// Persistent phase C. grid 256, 512 thr = 8 waves. out ring = HI ONLY now
// (al*B terms dropped; halves ring traffic + MFMA). Wvo kept split in regs.
// ---------------------------------------------------------------------------
__global__ __launch_bounds__(512) void k_phaseC(
    const u16* __restrict__ Wvh, const u16* __restrict__ Wvl,
    const float* __restrict__ Wx,
    const u16* __restrict__ hoh, const u16* __restrict__ hol,
    u16* __restrict__ ring_h,
    float* __restrict__ fdest, int dmode,
    u32* __restrict__ flags, u32* __restrict__ rel)
{
  __shared__ float VO_lds[128 * 256];        // [t][b*16+col]  128 KB
  __shared__ float vo_w[8][256];
  __shared__ float pctx[2][256];
  const int tid = threadIdx.x;
  const int lane = tid & 63, wv = tid >> 6;
  const int n0 = blockIdx.x * 16;
  const int r15 = lane & 15, kq = lane >> 4;
  const long kb = (long)wv * 512 + kq * 8;   // this lane's K base

  short8v Bh[16], Bl[16];
  {
    const u16* bh = Wvh + (long)(n0 + r15) * 4096 + kb;
    const u16* bl = Wvl + (long)(n0 + r15) * 4096 + kb;
    #pragma unroll
    for (int c = 0; c < 16; ++c) {
      Bh[c] = *(const short8v*)(bh + c * 32);
      Bl[c] = *(const short8v*)(bl + c * 32);
    }
    #pragma unroll
    for (int c = 0; c < 16; ++c) {
      asm volatile("" : "+v"(Bh[c]));
      asm volatile("" : "+v"(Bl[c]));
    }
  }
  const long abase = (long)r15 * 4096 + kb;  // A-frag base (row = batch r15)
  const int b8 = tid >> 4, col8 = tid & 15;  // (b, col) for tid<256

#define GBAR(n)                                                              \
  {                                                                          \
    asm volatile("s_waitcnt vmcnt(0)" ::: "memory");                         \
    __syncthreads();                                                         \
    if (tid == 0) {                                                          \
      atomswap32(&flags[(u32)blockIdx.x * 16], (n));                         \
      asm volatile("s_waitcnt vmcnt(0)" ::: "memory");                       \
    }                                                                        \
    if (blockIdx.x == 0) {                                                   \
      if (tid < 256) {                                                       \
        while (ldsc32(&flags[tid * 16]) < (n)) __builtin_amdgcn_s_sleep(1);  \
      }                                                                      \
      __syncthreads();                                                       \
      if (tid < 256) atomswap32(&rel[tid * 16], (n));                        \
    } else if (tid == 0) {                                                   \
      while (ldsc32(&rel[(u32)blockIdx.x * 16]) < (n))                       \
        __builtin_amdgcn_s_sleep(1);                                         \
    }                                                                        \
    __syncthreads();                                                         \
  }

  // pack this thread's hi with col-partner and atomic-store to coherent point
#define RING_STORE(slot, oval)                                               \
  {                                                                          \
    u16 hh_ = f2bf(oval);                                                    \
    u32 vh_ = hh_;                                                           \
    u32 ph_ = (u32)__shfl_xor((int)vh_, 1);                                  \
    if (!(col8 & 1)) {                                                       \
      long oi_ = (long)(slot) * 65536 + (long)b8 * 4096 + n0 + col8;         \
      atomswap32((u32*)&ring_h[oi_], vh_ | (ph_ << 16));                     \
    }                                                                        \
  }

  if (tid < 256) {
    float v = tanhf(bf2f(hoh[(long)b8 * 12288 + n0 + col8])
                  + bf2f(hol[(long)b8 * 12288 + n0 + col8]));
    RING_STORE(0, v)
    if (dmode == 0) fdest[(long)b8 * 4096 + n0 + col8] = v;
    else            fdest[(long)b8 * 128 * 4096 + n0 + col8] = v;
  }
  u32 bn = 1;
  GBAR(bn) ++bn;

#define MF(a, b) acc = __builtin_amdgcn_mfma_f32_16x16x32_bf16(a, b, acc, 0, 0, 0);

  for (int t = 0; t < 127; ++t) {
    const u16* ph = ring_h + (long)t * 65536 + abase;   // plain cached loads
    f32x4 acc = {0.f, 0.f, 0.f, 0.f};
    {
      short8v xh[8];
      #pragma unroll
      for (int c = 0; c < 8; ++c) xh[c] = *(const short8v*)(ph + c * 32);
      #pragma unroll
      for (int c = 0; c < 8; ++c) { MF(xh[c], Bh[c]) MF(xh[c], Bl[c]) }
    }
    {
      short8v xh[8];
      #pragma unroll
      for (int c = 0; c < 8; ++c) xh[c] = *(const short8v*)(ph + 256 + c * 32);
      #pragma unroll
      for (int c = 0; c < 8; ++c) { MF(xh[c], Bh[8 + c]) MF(xh[c], Bl[8 + c]) }
    }

    #pragma unroll
    for (int g = 0; g < 4; ++g)
      vo_w[wv][(kq * 4 + g) * 16 + r15] = acc[g];
    __syncthreads();
    float v = 0.f;
    if (tid < 256) {
      v = vo_w[0][tid] + vo_w[1][tid] + vo_w[2][tid] + vo_w[3][tid]
        + vo_w[4][tid] + vo_w[5][tid] + vo_w[6][tid] + vo_w[7][tid];
      VO_lds[t * 256 + tid] = v;
    }
    {
      const int p = tid >> 8, id = tid & 255;
      const int b = id >> 4;
      const float* wrow = &Wx[((long)(t + 1) * 16 + b) * 128];
      float ctx = 0.f;
      for (int tp = p; tp < t; tp += 2)
        ctx += wrow[tp] * VO_lds[tp * 256 + id];
      pctx[p][id] = ctx;
    }
    __syncthreads();
    if (tid < 256) {
      const float* wrow = &Wx[((long)(t + 1) * 16 + b8) * 128];
      long hix = ((long)(t + 1) * 16 + b8) * 12288 + n0 + col8;
      float o = tanhf(bf2f(hoh[hix]) + bf2f(hol[hix])
                      + pctx[0][tid] + pctx[1][tid] + wrow[t] * v);
      RING_STORE(t + 1, o)
      if (dmode == 0) fdest[((long)(t + 1) * 16 + b8) * 4096 + n0 + col8] = o;
      else            fdest[((long)b8 * 128 + (t + 1)) * 4096 + n0 + col8] = o;
    }
    if (t < 126) { GBAR(bn) ++bn; }
  }
#undef GBAR
#undef RING_STORE
#undef MF
}

// ---------------------------------------------------------------------------
extern "C" void kernel_launch(void* const* d_in, const int* in_sizes, int n_in,
                              void* d_out, int out_size, void* d_ws, size_t ws_size,
                              hipStream_t stream)
{
  (void)in_sizes; (void)n_in; (void)out_size;
  if (ws_size < 472383488UL) return;  // need ~451 MiB scratch
  char* ws = (char*)d_ws;
  u16* WT_hi = (u16*)(ws + 0UL);               // 96 MB
  u16* WT_lo = (u16*)(ws + 100663296UL);       // 96 MB
  u16* WV_hi = (u16*)(ws + 33554432UL);        // reuses dead WT rows
  u16* WV_lo = (u16*)(ws + 134217728UL);
  u16* QKOh  = (u16*)(ws + 201326592UL);       // [2048][12288] hi (48 MB)
  u16* QKOl  = (u16*)(ws + 251658240UL);       // lo (48 MB; HO cols only used)
  u16* Wvo_hi = (u16*)(ws + 301989888UL);      // 32 MB (reused per layer)
  u16* Wvo_lo = (u16*)(ws + 335544320UL);      // 32 MB
  u16* Hs_hi = (u16*)(ws + 369098752UL);       // 16 MB
  u16* Hs_lo = (u16*)(ws + 385875968UL);
  float* Sb   = (float*)(ws + 402653184UL);    // 1 MB
  float* Wmx  = (float*)(ws + 403701760UL);    // 1 MB
  float* OUT0 = (float*)(ws + 404754432UL);    // 32 MB
  u16* ring_h = (u16*)(ws + 438308864UL);      // 16 MB: 128 x [16][4096]
  u32* flg    = (u32*)(ws + 471859200UL);      // 16 KB (256 x 64B lines)
  u32* rel    = (u32*)(ws + 471875584UL);      // 16 KB (256 x 64B lines)
  float* dout = (float*)d_out;
  const float* x_flat = (const float*)d_in[0];

  for (int l = 0; l < 2; ++l) {
    const float* cw = (const float*)d_in[1 + l * 6];
    const float* cb = (const float*)d_in[2 + l * 6];
    const float* wq = (const float*)d_in[3 + l * 6];
    const float* wk = (const float*)d_in[4 + l * 6];
    const float* wv = (const float*)d_in[5 + l * 6];
    const float* wo = (const float*)d_in[6 + l * 6];
    const int cin = (l == 0) ? 17 : 32;

    // Phase A: ConvLSTM recurrence -> split h_vec rows
    hipLaunchKernelGGL(k_conv, dim3(256), dim3(256), 0, stream,
        cin, l, (l == 0) ? x_flat : OUT0, cw, cb, Hs_hi, Hs_lo);

    // Phase B1: transposes, then QK (1-MFMA, hi-only) + HO (3-MFMA split)
    hipLaunchKernelGGL(k_tsplit, dim3(16384), dim3(256), 0, stream,
        wq, WT_hi, WT_lo);
    hipLaunchKernelGGL(k_tsplit, dim3(16384), dim3(256), 0, stream,
        wk, WT_hi + 16777216UL, WT_lo + 16777216UL);
    hipLaunchKernelGGL(k_tsplit, dim3(16384), dim3(256), 0, stream,
        wo, WT_hi + 33554432UL, WT_lo + 33554432UL);
    hipLaunchKernelGGL((k_gemm256<1, false>), dim3(512), dim3(512), 0, stream,
        Hs_hi, Hs_hi, WT_hi, WT_hi, QKOh, (u16*)nullptr, 12288L, 64);
    hipLaunchKernelGGL((k_gemm256<3, true>), dim3(256), dim3(512), 0, stream,
        Hs_hi, Hs_lo, WT_hi + 33554432UL, WT_lo + 33554432UL,
        QKOh + 8192, QKOl + 8192, 12288L, 32);

    // Phase B2: composite Wvo^T = (wv @ wo_c)^T  (2-MFMA: A split, B hi)
    hipLaunchKernelGGL(k_tsplit, dim3(16384), dim3(256), 0, stream,
        wo + 16777216UL, WT_hi, WT_lo);                       // wo_c^T
    hipLaunchKernelGGL(k_split, dim3(16384), dim3(256), 0, stream, wv, WV_hi, WV_lo);
    hipLaunchKernelGGL((k_gemm256<2, true>), dim3(512), dim3(512), 0, stream,
        WT_hi, WT_lo, WV_hi, WV_hi, Wvo_hi, Wvo_lo, 4096L, 32);

    // Scores via batched 1-MFMA GEMM: S[b][t][t'] = Q[t,b,:]·K[t',b,:]
    hipLaunchKernelGGL((k_gemm<1>), dim3(1, 16), dim3(256), 0, stream,
        QKOh, QKOh, 196608L, 12288L, QKOh + 4096, QKOh + 4096, 196608L, 12288L,
        Sb, (u16*)nullptr, (u16*)nullptr, 128L, 16384L, 1, 0);
    hipLaunchKernelGGL(k_softmax, dim3(512), dim3(256), 0, stream, Sb, Wmx, flg, rel);

    // Phase C: ONE persistent kernel (hi-only ring)
    hipLaunchKernelGGL(k_phaseC, dim3(256), dim3(512), 0, stream,
        Wvo_hi, Wvo_lo, Wmx, QKOh + 8192, QKOl + 8192,
        ring_h, (l == 0) ? OUT0 : dout, l, flg, rel);
  }
}

// Round 13
// 4559.058 us; speedup vs baseline: 1.4909x; 1.0945x over previous
//
#include <hip/hip_runtime.h>

typedef unsigned short u16;
typedef unsigned int u32;
typedef __attribute__((ext_vector_type(8))) short short8v;   // 8 bf16 (4 VGPR) MFMA frag
typedef __attribute__((ext_vector_type(4))) float f32x4;     // MFMA acc
typedef __attribute__((ext_vector_type(8))) u16 ush8;
typedef __attribute__((ext_vector_type(4))) u16 ush4;

__device__ __forceinline__ u16 f2bf(float x) {               // RNE f32->bf16
  u32 u = __builtin_bit_cast(u32, x);
  return (u16)((u + 0x7FFFu + ((u >> 16) & 1u)) >> 16);
}
__device__ __forceinline__ float bf2f(u16 h) {
  u32 u = ((u32)h) << 16;
  return __builtin_bit_cast(float, u);
}
__device__ __forceinline__ float sigm(float x) { return 1.f / (1.f + expf(-x)); }

typedef const __attribute__((address_space(1))) void gv_t;
typedef __attribute__((address_space(3))) void lv_t;
__device__ __forceinline__ void gload16(const void* g, void* l) {
  __builtin_amdgcn_global_load_lds((gv_t*)g, (lv_t*)l, 16, 0, 0);
}

// --- device-coherent access helpers -----------------------------------------
__device__ __forceinline__ u32 ldsc32(const u32* p) {        // bypass L1/L2
  u32 v;
  asm volatile("global_load_dword %0, %1, off sc0 sc1\n\ts_waitcnt vmcnt(0)"
               : "=v"(v) : "v"(p) : "memory");
  return v;
}
// MALL coherent store: device-scope atomic swap, NO-RETURN form
__device__ __forceinline__ void atomswap32(u32* p, u32 v) {
  asm volatile("global_atomic_swap %0, %1, off" :: "v"(p), "v"(v) : "memory");
}

// ---------------------------------------------------------------------------
// ConvLSTM recurrence: one WG per (b, row). Vectorized LDS access:
// w relaid as [ch][ic][tap][4 gates] (3x ds_read_b128/ic), z via 1 read +
// 2 lane shuffles (edge cols = pad zeros).
// ---------------------------------------------------------------------------
__global__ __launch_bounds__(256) void k_conv(int cin, int xmode,
    const float* __restrict__ xin, const float* __restrict__ cw,
    const float* __restrict__ cb, u16* __restrict__ hhi, u16* __restrict__ hlo)
{
  __shared__ float zb[32 * 18];                 // cin x (16+2 pad)
  __shared__ __align__(16) float wb[6144];      // [ch][ic][tap][gate]
  __shared__ float bb[64];
  const int tid = threadIdx.x;
  const int b = blockIdx.x >> 4, r = blockIdx.x & 15;
  const int ch = tid >> 4, col = tid & 15;
  const int cx = cin - 16;
  for (int i = tid; i < 64 * cin * 3; i += 256) {
    int tap = i % 3, tmp = i / 3;
    int ic = tmp % cin, oc = tmp / cin;
    wb[(((oc & 15) * cin + ic) * 3 + tap) * 4 + (oc >> 4)] = cw[i];
  }
  if (tid < 64) bb[tid] = cb[tid];
  for (int i = tid; i < cin * 18; i += 256) zb[i] = 0.f;  // includes pad cols
  __syncthreads();
  float h = 0.f, c = 0.f;
  const int lane = tid & 63;
  for (int t = 0; t < 128; ++t) {
    if (xmode == 0) {
      if (ch == 0) zb[col + 1] = xin[((long)b * 128 + t) * 256 + r * 16 + col];
    } else {
      zb[ch * 18 + col + 1] = xin[((long)t * 16 + b) * 4096 + r * 256 + ch * 16 + col];
    }
    zb[(cx + ch) * 18 + col + 1] = h;
    __syncthreads();
    float a0 = bb[ch], a1 = bb[16 + ch], a2 = bb[32 + ch], a3 = bb[48 + ch];
    for (int ic = 0; ic < cin; ++ic) {
      float z1 = zb[ic * 18 + col + 1];
      float z0 = __shfl(z1, lane - 1);
      float z2 = __shfl(z1, lane + 1);
      if (col == 0) z0 = 0.f;
      if (col == 15) z2 = 0.f;
      const float4* wp = (const float4*)&wb[(ch * cin + ic) * 12];
      float4 w0 = wp[0], w1 = wp[1], w2 = wp[2];
      a0 += z0 * w0.x + z1 * w1.x + z2 * w2.x;
      a1 += z0 * w0.y + z1 * w1.y + z2 * w2.y;
      a2 += z0 * w0.z + z1 * w1.z + z2 * w2.z;
      a3 += z0 * w0.w + z1 * w1.w + z2 * w2.w;
    }
    __syncthreads();
    c = sigm(a1) * c + sigm(a0) * tanhf(a2);   // i,f,g,o gate order
    h = sigm(a3) * tanhf(c);
    long idx = ((long)t * 16 + b) * 4096 + (long)r * 256 + ch * 16 + col;
    u16 hh = f2bf(h);
    hhi[idx] = hh;
    hlo[idx] = f2bf(h - bf2f(hh));
  }
}

// ---------------------------------------------------------------------------
// Transpose + split x3 (fused): W[4096][4096] fp32 -> WT_hi/lo[n][k] bf16
// blockIdx.y selects source/destination third.
// ---------------------------------------------------------------------------
__global__ __launch_bounds__(256) void k_tsplit3(
    const float* __restrict__ W0, const float* __restrict__ W1,
    const float* __restrict__ W2, u16* __restrict__ hi, u16* __restrict__ lo)
{
  __shared__ float tb[32][33];
  const int y = blockIdx.y;
  const float* W = (y == 0) ? W0 : (y == 1) ? W1 : W2;
  u16* hid = hi + (unsigned long)y * 16777216UL;
  u16* lod = lo + (unsigned long)y * 16777216UL;
  const int tn = blockIdx.x & 127, tk = blockIdx.x >> 7;
  const int n0 = tn * 32, k0 = tk * 32;
  const int lr = threadIdx.x >> 5, lc = threadIdx.x & 31;
  #pragma unroll
  for (int i = 0; i < 4; ++i)
    tb[lr + i * 8][lc] = W[(long)(k0 + lr + i * 8) * 4096 + n0 + lc];
  __syncthreads();
  #pragma unroll
  for (int i = 0; i < 4; ++i) {
    int n = lr + i * 8;
    float v = tb[lc][n];
    long idx = (long)(n0 + n) * 4096 + k0 + lc;
    u16 h = f2bf(v);
    hid[idx] = h;
    lod[idx] = f2bf(v - bf2f(h));
  }
}

// Single-weight transpose+split (wo_c)
__global__ __launch_bounds__(256) void k_tsplit(const float* __restrict__ W,
    u16* __restrict__ hi, u16* __restrict__ lo)
{
  __shared__ float tb[32][33];
  const int tn = blockIdx.x & 127, tk = blockIdx.x >> 7;
  const int n0 = tn * 32, k0 = tk * 32;
  const int lr = threadIdx.x >> 5, lc = threadIdx.x & 31;
  #pragma unroll
  for (int i = 0; i < 4; ++i)
    tb[lr + i * 8][lc] = W[(long)(k0 + lr + i * 8) * 4096 + n0 + lc];
  __syncthreads();
  #pragma unroll
  for (int i = 0; i < 4; ++i) {
    int n = lr + i * 8;
    float v = tb[lc][n];
    long idx = (long)(n0 + n) * 4096 + k0 + lc;
    u16 h = f2bf(v);
    hi[idx] = h;
    lo[idx] = f2bf(v - bf2f(h));
  }
}

// Elementwise split (no transpose) for wv
__global__ __launch_bounds__(256) void k_split(const float* __restrict__ W,
    u16* __restrict__ hi, u16* __restrict__ lo)
{
  long i = ((long)blockIdx.x * 256 + threadIdx.x) * 4;
  const float4 v = *(const float4*)&W[i];
  u16 h0 = f2bf(v.x), h1 = f2bf(v.y), h2 = f2bf(v.z), h3 = f2bf(v.w);
  ush4 hv = {h0, h1, h2, h3};
  ush4 lv = {f2bf(v.x - bf2f(h0)), f2bf(v.y - bf2f(h1)),
             f2bf(v.z - bf2f(h2)), f2bf(v.w - bf2f(h3))};
  *(ush4*)&hi[i] = hv;
  *(ush4*)&lo[i] = lv;
}

// ---------------------------------------------------------------------------
// Scores GEMM, K-split x8: 128x128 tile, batch = blockIdx.y, K-slice =
// blockIdx.z (512 each); partials to Sp slice z. 2-phase dbuf within slice.
// ---------------------------------------------------------------------------
__global__ __launch_bounds__(256) void k_scores(
    const u16* __restrict__ Ahi, long lda, long aBS,
    const u16* __restrict__ Bhi, long ldb, long bBS,
    float* __restrict__ Sp)
{
  __shared__ __align__(16) u16 lds[2][16384];   // per buf: PA @0, PB @8192
  const int tid = threadIdx.x;
  const int lane = tid & 63;
  const int wv = tid >> 6;
  const long aOff = (long)blockIdx.y * aBS;
  const long bOff = (long)blockIdx.y * bBS;
  const long cOff = (long)blockIdx.y * 16384 + (long)blockIdx.z * 262144;
  const int kbase = blockIdx.z * 512;

  const int l8 = lane >> 3;
  const int cslot = (lane & 7) ^ l8;
  const int ck = (cslot & 3) * 8;
  // hi-only inputs: both halves of the lane set read hi (cslot<4 and >=4 same)
  const u16* aSrc = Ahi + aOff + (wv * 32 + l8) * lda + ck;
  const u16* bSrc = Bhi + bOff + (wv * 32 + l8) * ldb + ck;
  const int ldsAo = wv * 2048;
  const int ldsBo = 8192 + wv * 2048;

  const int r15 = lane & 15, kq = lane >> 4;
  const int s7 = r15 & 7;
  const int oHi = (kq ^ s7) * 8;
  const int aQ = (wv >> 1) * 64;
  const int bQ = (wv & 1) * 64;

  f32x4 acc[4][4] = {};

#define STAGE(buf, kofs)                                                     \
  {                                                                          \
    const u16* sa = aSrc + (kofs);                                           \
    const u16* sb = bSrc + (kofs);                                           \
    u16* la = &lds[buf][ldsAo];                                              \
    u16* lb = &lds[buf][ldsBo];                                              \
    gload16(sa,            la);        gload16(sa +  8 * lda, la + 512);     \
    gload16(sa + 16 * lda, la + 1024); gload16(sa + 24 * lda, la + 1536);    \
    gload16(sb,            lb);        gload16(sb +  8 * ldb, lb + 512);     \
    gload16(sb + 16 * ldb, lb + 1024); gload16(sb + 24 * ldb, lb + 1536);    \
  }

  STAGE(0, kbase)
  __syncthreads();
  int cur = 0;
  for (int k0 = kbase; k0 < kbase + 512; k0 += 32) {
    if (k0 + 32 < kbase + 512) STAGE(cur ^ 1, k0 + 32)
    const u16* L = &lds[cur][0];
    short8v bh[4];
    #pragma unroll
    for (int j = 0; j < 4; ++j)
      bh[j] = *(const short8v*)&L[8192 + (bQ + j * 16 + r15) * 64 + oHi];
    #pragma unroll
    for (int i = 0; i < 4; ++i) {
      short8v ah = *(const short8v*)&L[(aQ + i * 16 + r15) * 64 + oHi];
      #pragma unroll
      for (int j = 0; j < 4; ++j)
        acc[i][j] = __builtin_amdgcn_mfma_f32_16x16x32_bf16(ah, bh[j], acc[i][j], 0, 0, 0);
    }
    __syncthreads();
    cur ^= 1;
  }
#undef STAGE
  const long row0 = aQ, col0 = bQ;
  #pragma unroll
  for (int i = 0; i < 4; ++i)
    #pragma unroll
    for (int j = 0; j < 4; ++j) {
      long rr = row0 + i * 16 + kq * 4;
      long cc = col0 + j * 16 + r15;
      #pragma unroll
      for (int g = 0; g < 4; ++g)
        Sp[cOff + (rr + g) * 128 + cc] = acc[i][j][g];
    }
}

// ---------------------------------------------------------------------------
// 256x128-tile GEMM, 3-buffer LDS rotation, counted vmcnt(6), 1 barrier/tile.
// NM = #MFMAs per frag pair; LOOUT: also write split-lo C. Grid div by 8.
// ---------------------------------------------------------------------------
template<int NM, bool LOOUT>
__global__ __launch_bounds__(512) void k_gemm256(
    const u16* __restrict__ Ahi, const u16* __restrict__ Alo,
    const u16* __restrict__ Bhi, const u16* __restrict__ Blo,
    u16* __restrict__ Chi, u16* __restrict__ Clo, long ldc, int nTc)
{
  __shared__ __align__(16) u16 lds[73728];   // 3 bufs x (A 16384 | B 8192)
  const int tid = threadIdx.x, lane = tid & 63, wv = tid >> 6;
  const int nwg = gridDim.x;
  const int bid2 = (blockIdx.x & 7) * (nwg >> 3) + (blockIdx.x >> 3);
  const int nT = bid2 % nTc, mT = bid2 / nTc;
  const long aRow0 = (long)mT * 256, bRow0 = (long)nT * 128;

  const int l8 = lane >> 3, cslot = (lane & 7) ^ l8, ck = (cslot & 3) * 8;
  const u16* aSrc = ((cslot < 4) ? Ahi : Alo) + (aRow0 + wv * 32 + l8) * 4096 + ck;
  const u16* bSrc = ((cslot < 4) ? Bhi : Blo) + (bRow0 + wv * 16 + l8) * 4096 + ck;
  const int laO = wv * 2048;            // A: wave stages 32 rows x 64 u16
  const int lbO = 16384 + wv * 1024;    // B: wave stages 16 rows x 64 u16

  const int r15 = lane & 15, kq = lane >> 4, s7 = r15 & 7;
  const int oHi = (kq ^ s7) * 8, oLo = ((4 + kq) ^ s7) * 8;
  const int wm = wv >> 1, wn = wv & 1;
  f32x4 acc[4][4] = {};

#define STG(buf, kofs)                                                       \
  {                                                                          \
    const u16* sa = aSrc + (kofs);                                           \
    const u16* sb = bSrc + (kofs);                                           \
    u16* la = &lds[(buf) * 24576 + laO];                                     \
    u16* lb = &lds[(buf) * 24576 + lbO];                                     \
    gload16(sa,             la);       gload16(sa +  8 * 4096, la + 512);    \
    gload16(sa + 16 * 4096, la + 1024); gload16(sa + 24 * 4096, la + 1536);  \
    gload16(sb,             lb);       gload16(sb +  8 * 4096, lb + 512);    \
  }

  STG(0, 0) STG(1, 32)                  // tiles 0,1 in flight (12 loads)
  for (int kt = 0; kt < 128; ++kt) {
    if (kt < 127) { asm volatile("s_waitcnt vmcnt(6)" ::: "memory"); }
    else          { asm volatile("s_waitcnt vmcnt(0)" ::: "memory"); }
    __builtin_amdgcn_sched_barrier(0);
    __builtin_amdgcn_s_barrier();       // all waves' tile-kt loads complete
    const int bb = (kt % 3) * 24576;
    if (kt < 126) STG((kt + 2) % 3, (kt + 2) * 32)   // 2-deep prefetch
    short8v ah[4], al[4], bh[4], bl[4];
    #pragma unroll
    for (int j = 0; j < 4; ++j) {
      int rb = bb + 16384 + (wn * 64 + j * 16 + r15) * 64;
      bh[j] = *(const short8v*)&lds[rb + oHi];
      if (NM >= 3) bl[j] = *(const short8v*)&lds[rb + oLo];
    }
    #pragma unroll
    for (int i = 0; i < 4; ++i) {
      int ra = bb + (wm * 64 + i * 16 + r15) * 64;
      ah[i] = *(const short8v*)&lds[ra + oHi];
      if (NM >= 2) al[i] = *(const short8v*)&lds[ra + oLo];
    }
    #pragma unroll
    for (int i = 0; i < 4; ++i)
      #pragma unroll
      for (int j = 0; j < 4; ++j) {
        acc[i][j] = __builtin_amdgcn_mfma_f32_16x16x32_bf16(ah[i], bh[j], acc[i][j], 0, 0, 0);
        if (NM >= 3) acc[i][j] = __builtin_amdgcn_mfma_f32_16x16x32_bf16(ah[i], bl[j], acc[i][j], 0, 0, 0);
        if (NM >= 2) acc[i][j] = __builtin_amdgcn_mfma_f32_16x16x32_bf16(al[i], bh[j], acc[i][j], 0, 0, 0);
      }
  }
#undef STG
  // epilogue: split-bf16 store (m89 layout)
  const long row0 = aRow0 + wm * 64;
  const long col0 = bRow0 + wn * 64;
  #pragma unroll
  for (int i = 0; i < 4; ++i)
    #pragma unroll
    for (int j = 0; j < 4; ++j) {
      long rr = row0 + i * 16 + kq * 4;
      long cc = col0 + j * 16 + r15;
      #pragma unroll
      for (int g = 0; g < 4; ++g) {
        float v = acc[i][j][g];
        long idx = (rr + g) * ldc + cc;
        u16 h = f2bf(v);
        Chi[idx] = h;
        if (LOOUT) Clo[idx] = f2bf(v - bf2f(h));
      }
    }
}

// Softmax over strictly-past scores (sums 8 K-slice partials) -> Wx[t][b][t'];
// also zeroes the barrier arrival/release lines via MALL atomics.
__global__ __launch_bounds__(256) void k_softmax(const float* __restrict__ Sp,
    float* __restrict__ Wx, u32* __restrict__ flags, u32* __restrict__ rel)
{
  if (blockIdx.x == 0) atomswap32(&flags[threadIdx.x * 16], 0);
  if (blockIdx.x == 1) atomswap32(&rel[threadIdx.x * 16], 0);
  const int wv = threadIdx.x >> 6, lane = threadIdx.x & 63;
  const int idx = blockIdx.x * 4 + wv;        // = b*128 + t
  const int b = idx >> 7, t = idx & 127;
  const float* row = &Sp[(long)idx * 128];
  float s0 = 0.f, s1 = 0.f;
  #pragma unroll
  for (int s = 0; s < 8; ++s) {
    s0 += row[s * 262144 + lane];
    s1 += row[s * 262144 + lane + 64];
  }
  float v0 = (lane < t) ? s0 * 0.015625f : -1e30f;
  float v1 = (lane + 64 < t) ? s1 * 0.015625f : -1e30f;
  float m = fmaxf(v0, v1);
  #pragma unroll
  for (int off = 32; off; off >>= 1) m = fmaxf(m, __shfl_xor(m, off));
  float e0 = (lane < t) ? expf(v0 - m) : 0.f;
  float e1 = (lane + 64 < t) ? expf(v1 - m) : 0.f;
  float s = e0 + e1;
  #pragma unroll
  for (int off = 32; off; off >>= 1) s += __shfl_xor(s, off);
  float inv = 1.f / fmaxf(s, 1e-9f);
  float* wr = &Wx[((long)t * 16 + b) * 128];
  wr[lane] = e0 * inv;
  wr[lane + 64] = e1 * inv;
}

// ---------------------------------------------------------------------------
// Persistent phase C. grid 256, 512 thr = 8 waves. hi-only out ring.
// Mix-partial now computed BEFORE the MFMA cluster (independent of out_t)
// so it hides under the A-refill latency; one fewer syncthreads/step.
// ---------------------------------------------------------------------------
__global__ __launch_bounds__(512) void k_phaseC(
    const u16* __restrict__ Wvh, const u16* __restrict__ Wvl,
    const float* __restrict__ Wx,
    const u16* __restrict__ hoh, const u16* __restrict__ hol,
    u16* __restrict__ ring_h,
    float* __restrict__ fdest, int dmode,
    u32* __restrict__ flags, u32* __restrict__ rel)
{
  __shared__ float VO_lds[128 * 256];        // [t][b*16+col]  128 KB
  __shared__ float vo_w[8][256];
  __shared__ float pctx[2][256];
  const int tid = threadIdx.x;
  const int lane = tid & 63, wv = tid >> 6;
  const int n0 = blockIdx.x * 16;
  const int r15 = lane & 15, kq = lane >> 4;
  const long kb = (long)wv * 512 + kq * 8;   // this lane's K base

  short8v Bh[16], Bl[16];
  {
    const u16* bh = Wvh + (long)(n0 + r15) * 4096 + kb;
    const u16* bl = Wvl + (long)(n0 + r15) * 4096 + kb;
    #pragma unroll
    for (int c = 0; c < 16; ++c) {
      Bh[c] = *(const short8v*)(bh + c * 32);
      Bl[c] = *(const short8v*)(bl + c * 32);
    }
    #pragma unroll
    for (int c = 0; c < 16; ++c) {
      asm volatile("" : "+v"(Bh[c]));
      asm volatile("" : "+v"(Bl[c]));
    }
  }
  const long abase = (long)r15 * 4096 + kb;  // A-frag base (row = batch r15)
  const int b8 = tid >> 4, col8 = tid & 15;  // (b, col) for tid<256

#define GBAR(n)                                                              \
  {                                                                          \
    asm volatile("s_waitcnt vmcnt(0)" ::: "memory");                         \
    __syncthreads();                                                         \
    if (tid == 0) {                                                          \
      atomswap32(&flags[(u32)blockIdx.x * 16], (n));                         \
      asm volatile("s_waitcnt vmcnt(0)" ::: "memory");                       \
    }                                                                        \
    if (blockIdx.x == 0) {                                                   \
      if (tid < 256) {                                                       \
        while (ldsc32(&flags[tid * 16]) < (n)) __builtin_amdgcn_s_sleep(1);  \
      }                                                                      \
      __syncthreads();                                                       \
      if (tid < 256) atomswap32(&rel[tid * 16], (n));                        \
    } else if (tid == 0) {                                                   \
      while (ldsc32(&rel[(u32)blockIdx.x * 16]) < (n))                       \
        __builtin_amdgcn_s_sleep(1);                                         \
    }                                                                        \
    __syncthreads();                                                         \
  }

#define RING_STORE(slot, oval)                                               \
  {                                                                          \
    u16 hh_ = f2bf(oval);                                                    \
    u32 vh_ = hh_;                                                           \
    u32 ph_ = (u32)__shfl_xor((int)vh_, 1);                                  \
    if (!(col8 & 1)) {                                                       \
      long oi_ = (long)(slot) * 65536 + (long)b8 * 4096 + n0 + col8;         \
      atomswap32((u32*)&ring_h[oi_], vh_ | (ph_ << 16));                     \
    }                                                                        \
  }

  if (tid < 256) {
    float v = tanhf(bf2f(hoh[(long)b8 * 12288 + n0 + col8])
                  + bf2f(hol[(long)b8 * 12288 + n0 + col8]));
    RING_STORE(0, v)
    if (dmode == 0) fdest[(long)b8 * 4096 + n0 + col8] = v;
    else            fdest[(long)b8 * 128 * 4096 + n0 + col8] = v;
  }
  u32 bn = 1;
  GBAR(bn) ++bn;

#define MF(a, b) acc = __builtin_amdgcn_mfma_f32_16x16x32_bf16(a, b, acc, 0, 0, 0);

  for (int t = 0; t < 127; ++t) {
    const u16* ph = ring_h + (long)t * 65536 + abase;   // plain cached loads
    // issue A-loads first (no deps) ...
    short8v xh[16];
    #pragma unroll
    for (int c = 0; c < 16; ++c) xh[c] = *(const short8v*)(ph + c * 32);
    // ... mix-partial (indep of out_t) hides under the load latency
    {
      const int p = tid >> 8, id = tid & 255;
      const int bm = id >> 4;
      const float* wrowm = &Wx[((long)(t + 1) * 16 + bm) * 128];
      float ctx = 0.f;
      for (int tp = p; tp < t; tp += 2)
        ctx += wrowm[tp] * VO_lds[tp * 256 + id];
      pctx[p][id] = ctx;
    }
    f32x4 acc = {0.f, 0.f, 0.f, 0.f};
    #pragma unroll
    for (int c = 0; c < 16; ++c) { MF(xh[c], Bh[c]) MF(xh[c], Bl[c]) }
    #pragma unroll
    for (int g = 0; g < 4; ++g)
      vo_w[wv][(kq * 4 + g) * 16 + r15] = acc[g];
    __syncthreads();
    if (tid < 256) {
      float v = vo_w[0][tid] + vo_w[1][tid] + vo_w[2][tid] + vo_w[3][tid]
              + vo_w[4][tid] + vo_w[5][tid] + vo_w[6][tid] + vo_w[7][tid];
      VO_lds[t * 256 + tid] = v;
      const float* wrow = &Wx[((long)(t + 1) * 16 + b8) * 128];
      long hix = ((long)(t + 1) * 16 + b8) * 12288 + n0 + col8;
      float o = tanhf(bf2f(hoh[hix]) + bf2f(hol[hix])
                      + pctx[0][tid] + pctx[1][tid] + wrow[t] * v);
      RING_STORE(t + 1, o)
      if (dmode == 0) fdest[((long)(t + 1) * 16 + b8) * 4096 + n0 + col8] = o;
      else            fdest[((long)b8 * 128 + (t + 1)) * 4096 + n0 + col8] = o;
    }
    if (t < 126) { GBAR(bn) ++bn; }
  }
#undef GBAR
#undef RING_STORE
#undef MF
}

// ---------------------------------------------------------------------------
extern "C" void kernel_launch(void* const* d_in, const int* in_sizes, int n_in,
                              void* d_out, int out_size, void* d_ws, size_t ws_size,
                              hipStream_t stream)
{
  (void)in_sizes; (void)n_in; (void)out_size;
  if (ws_size < 472383488UL) return;  // need ~451 MiB scratch
  char* ws = (char*)d_ws;
  u16* WT_hi = (u16*)(ws + 0UL);               // 96 MB
  u16* WT_lo = (u16*)(ws + 100663296UL);       // 96 MB
  u16* WV_hi = (u16*)(ws + 33554432UL);        // reuses dead WT rows
  u16* WV_lo = (u16*)(ws + 134217728UL);
  u16* QKOh  = (u16*)(ws + 201326592UL);       // [2048][12288] hi (48 MB)
  u16* QKOl  = (u16*)(ws + 251658240UL);       // lo (HO cols only used)
  u16* Wvo_hi = (u16*)(ws + 301989888UL);      // 32 MB (reused per layer)
  u16* Wvo_lo = (u16*)(ws + 335544320UL);      // 32 MB
  u16* Hs_hi = (u16*)(ws + 369098752UL);       // 16 MB
  u16* Hs_lo = (u16*)(ws + 385875968UL);
  float* Wmx  = (float*)(ws + 403701760UL);    // 1 MB
  float* OUT0 = (float*)(ws + 404754432UL);    // 32 MB
  u16* ring_h = (u16*)(ws + 438308864UL);      // 16 MB: 128 x [16][4096]
  float* Sp   = (float*)(ws + 455086080UL);    // 8 MB: 8 K-slices x 16x128x128
  u32* flg    = (u32*)(ws + 471859200UL);      // 16 KB (256 x 64B lines)
  u32* rel    = (u32*)(ws + 471875584UL);      // 16 KB (256 x 64B lines)
  float* dout = (float*)d_out;
  const float* x_flat = (const float*)d_in[0];

  for (int l = 0; l < 2; ++l) {
    const float* cw = (const float*)d_in[1 + l * 6];
    const float* cb = (const float*)d_in[2 + l * 6];
    const float* wq = (const float*)d_in[3 + l * 6];
    const float* wk = (const float*)d_in[4 + l * 6];
    const float* wv = (const float*)d_in[5 + l * 6];
    const float* wo = (const float*)d_in[6 + l * 6];
    const int cin = (l == 0) ? 17 : 32;

    // Phase A: ConvLSTM recurrence -> split h_vec rows
    hipLaunchKernelGGL(k_conv, dim3(256), dim3(256), 0, stream,
        cin, l, (l == 0) ? x_flat : OUT0, cw, cb, Hs_hi, Hs_lo);

    // Phase B1: fused transposes, then QK (1-MFMA hi) + HO (3-MFMA split)
    hipLaunchKernelGGL(k_tsplit3, dim3(16384, 3), dim3(256), 0, stream,
        wq, wk, wo, WT_hi, WT_lo);
    hipLaunchKernelGGL((k_gemm256<1, false>), dim3(512), dim3(512), 0, stream,
        Hs_hi, Hs_hi, WT_hi, WT_hi, QKOh, (u16*)nullptr, 12288L, 64);
    hipLaunchKernelGGL((k_gemm256<3, true>), dim3(256), dim3(512), 0, stream,
        Hs_hi, Hs_lo, WT_hi + 33554432UL, WT_lo + 33554432UL,
        QKOh + 8192, QKOl + 8192, 12288L, 32);

    // Phase B2: composite Wvo^T = (wv @ wo_c)^T  (2-MFMA: A split, B hi)
    hipLaunchKernelGGL(k_tsplit, dim3(16384), dim3(256), 0, stream,
        wo + 16777216UL, WT_hi, WT_lo);                       // wo_c^T
    hipLaunchKernelGGL(k_split, dim3(16384), dim3(256), 0, stream, wv, WV_hi, WV_lo);
    hipLaunchKernelGGL((k_gemm256<2, true>), dim3(512), dim3(512), 0, stream,
        WT_hi, WT_lo, WV_hi, WV_hi, Wvo_hi, Wvo_lo, 4096L, 32);

    // Scores, K-split x8: S[b][t][t'] partials then summed in softmax
    hipLaunchKernelGGL(k_scores, dim3(1, 16, 8), dim3(256), 0, stream,
        QKOh, 12288L, 196608L, QKOh + 4096, 12288L, 196608L, Sp);
    hipLaunchKernelGGL(k_softmax, dim3(512), dim3(256), 0, stream, Sp, Wmx, flg, rel);

    // Phase C: ONE persistent kernel (hi-only ring)
    hipLaunchKernelGGL(k_phaseC, dim3(256), dim3(512), 0, stream,
        Wvo_hi, Wvo_lo, Wmx, QKOh + 8192, QKOl + 8192,
        ring_h, (l == 0) ? OUT0 : dout, l, flg, rel);
  }
}

// Round 14
// 4082.928 us; speedup vs baseline: 1.6647x; 1.1166x over previous
//
#include <hip/hip_runtime.h>

typedef unsigned short u16;
typedef unsigned int u32;
typedef __attribute__((ext_vector_type(8))) short short8v;   // 8 bf16 (4 VGPR) MFMA frag
typedef __attribute__((ext_vector_type(4))) float f32x4;     // MFMA acc
typedef __attribute__((ext_vector_type(8))) u16 ush8;
typedef __attribute__((ext_vector_type(4))) u16 ush4;

__device__ __forceinline__ u16 f2bf(float x) {               // RNE f32->bf16
  u32 u = __builtin_bit_cast(u32, x);
  return (u16)((u + 0x7FFFu + ((u >> 16) & 1u)) >> 16);
}
__device__ __forceinline__ float bf2f(u16 h) {
  u32 u = ((u32)h) << 16;
  return __builtin_bit_cast(float, u);
}
__device__ __forceinline__ float sigm(float x) { return 1.f / (1.f + expf(-x)); }

typedef const __attribute__((address_space(1))) void gv_t;
typedef __attribute__((address_space(3))) void lv_t;
__device__ __forceinline__ void gload16(const void* g, void* l) {
  __builtin_amdgcn_global_load_lds((gv_t*)g, (lv_t*)l, 16, 0, 0);
}

// --- device-coherent access helpers -----------------------------------------
__device__ __forceinline__ u32 ldsc32(const u32* p) {        // bypass L1/L2
  u32 v;
  asm volatile("global_load_dword %0, %1, off sc0 sc1\n\ts_waitcnt vmcnt(0)"
               : "=v"(v) : "v"(p) : "memory");
  return v;
}
// MALL coherent store: device-scope atomic swap, NO-RETURN form
__device__ __forceinline__ void atomswap32(u32* p, u32 v) {
  asm volatile("global_atomic_swap %0, %1, off" :: "v"(p), "v"(v) : "memory");
}

// ---------------------------------------------------------------------------
// ConvLSTM recurrence: one WG per (b, row). Vectorized LDS access.
// ---------------------------------------------------------------------------
__global__ __launch_bounds__(256) void k_conv(int cin, int xmode,
    const float* __restrict__ xin, const float* __restrict__ cw,
    const float* __restrict__ cb, u16* __restrict__ hhi, u16* __restrict__ hlo)
{
  __shared__ float zb[32 * 18];                 // cin x (16+2 pad)
  __shared__ __align__(16) float wb[6144];      // [ch][ic][tap][gate]
  __shared__ float bb[64];
  const int tid = threadIdx.x;
  const int b = blockIdx.x >> 4, r = blockIdx.x & 15;
  const int ch = tid >> 4, col = tid & 15;
  const int cx = cin - 16;
  for (int i = tid; i < 64 * cin * 3; i += 256) {
    int tap = i % 3, tmp = i / 3;
    int ic = tmp % cin, oc = tmp / cin;
    wb[(((oc & 15) * cin + ic) * 3 + tap) * 4 + (oc >> 4)] = cw[i];
  }
  if (tid < 64) bb[tid] = cb[tid];
  for (int i = tid; i < cin * 18; i += 256) zb[i] = 0.f;  // includes pad cols
  __syncthreads();
  float h = 0.f, c = 0.f;
  const int lane = tid & 63;
  for (int t = 0; t < 128; ++t) {
    if (xmode == 0) {
      if (ch == 0) zb[col + 1] = xin[((long)b * 128 + t) * 256 + r * 16 + col];
    } else {
      zb[ch * 18 + col + 1] = xin[((long)t * 16 + b) * 4096 + r * 256 + ch * 16 + col];
    }
    zb[(cx + ch) * 18 + col + 1] = h;
    __syncthreads();
    float a0 = bb[ch], a1 = bb[16 + ch], a2 = bb[32 + ch], a3 = bb[48 + ch];
    for (int ic = 0; ic < cin; ++ic) {
      float z1 = zb[ic * 18 + col + 1];
      float z0 = __shfl(z1, lane - 1);
      float z2 = __shfl(z1, lane + 1);
      if (col == 0) z0 = 0.f;
      if (col == 15) z2 = 0.f;
      const float4* wp = (const float4*)&wb[(ch * cin + ic) * 12];
      float4 w0 = wp[0], w1 = wp[1], w2 = wp[2];
      a0 += z0 * w0.x + z1 * w1.x + z2 * w2.x;
      a1 += z0 * w0.y + z1 * w1.y + z2 * w2.y;
      a2 += z0 * w0.z + z1 * w1.z + z2 * w2.z;
      a3 += z0 * w0.w + z1 * w1.w + z2 * w2.w;
    }
    __syncthreads();
    c = sigm(a1) * c + sigm(a0) * tanhf(a2);   // i,f,g,o gate order
    h = sigm(a3) * tanhf(c);
    long idx = ((long)t * 16 + b) * 4096 + (long)r * 256 + ch * 16 + col;
    u16 hh = f2bf(h);
    hhi[idx] = hh;
    hlo[idx] = f2bf(h - bf2f(hh));
  }
}

// ---------------------------------------------------------------------------
// Transpose + split x3 (fused): W[4096][4096] fp32 -> WT_hi/lo[n][k] bf16
// ---------------------------------------------------------------------------
__global__ __launch_bounds__(256) void k_tsplit3(
    const float* __restrict__ W0, const float* __restrict__ W1,
    const float* __restrict__ W2, u16* __restrict__ hi, u16* __restrict__ lo)
{
  __shared__ float tb[32][33];
  const int y = blockIdx.y;
  const float* W = (y == 0) ? W0 : (y == 1) ? W1 : W2;
  u16* hid = hi + (unsigned long)y * 16777216UL;
  u16* lod = lo + (unsigned long)y * 16777216UL;
  const int tn = blockIdx.x & 127, tk = blockIdx.x >> 7;
  const int n0 = tn * 32, k0 = tk * 32;
  const int lr = threadIdx.x >> 5, lc = threadIdx.x & 31;
  #pragma unroll
  for (int i = 0; i < 4; ++i)
    tb[lr + i * 8][lc] = W[(long)(k0 + lr + i * 8) * 4096 + n0 + lc];
  __syncthreads();
  #pragma unroll
  for (int i = 0; i < 4; ++i) {
    int n = lr + i * 8;
    float v = tb[lc][n];
    long idx = (long)(n0 + n) * 4096 + k0 + lc;
    u16 h = f2bf(v);
    hid[idx] = h;
    lod[idx] = f2bf(v - bf2f(h));
  }
}

// Fused prep for B2: y==0 transpose+split wo_c; y==1 elementwise split wv.
__global__ __launch_bounds__(256) void k_prepB2(
    const float* __restrict__ Woc, const float* __restrict__ Wv,
    u16* __restrict__ thi, u16* __restrict__ tlo,
    u16* __restrict__ vhi, u16* __restrict__ vlo)
{
  if (blockIdx.y == 1) {
    long i = ((long)blockIdx.x * 256 + threadIdx.x) * 4;
    const float4 v = *(const float4*)&Wv[i];
    u16 h0 = f2bf(v.x), h1 = f2bf(v.y), h2 = f2bf(v.z), h3 = f2bf(v.w);
    ush4 hv = {h0, h1, h2, h3};
    ush4 lv = {f2bf(v.x - bf2f(h0)), f2bf(v.y - bf2f(h1)),
               f2bf(v.z - bf2f(h2)), f2bf(v.w - bf2f(h3))};
    *(ush4*)&vhi[i] = hv;
    *(ush4*)&vlo[i] = lv;
    return;
  }
  __shared__ float tb[32][33];
  const int tn = blockIdx.x & 127, tk = blockIdx.x >> 7;
  const int n0 = tn * 32, k0 = tk * 32;
  const int lr = threadIdx.x >> 5, lc = threadIdx.x & 31;
  #pragma unroll
  for (int i = 0; i < 4; ++i)
    tb[lr + i * 8][lc] = Woc[(long)(k0 + lr + i * 8) * 4096 + n0 + lc];
  __syncthreads();
  #pragma unroll
  for (int i = 0; i < 4; ++i) {
    int n = lr + i * 8;
    float v = tb[lc][n];
    long idx = (long)(n0 + n) * 4096 + k0 + lc;
    u16 h = f2bf(v);
    thi[idx] = h;
    tlo[idx] = f2bf(v - bf2f(h));
  }
}

// ---------------------------------------------------------------------------
// Scores GEMM, K-split x8 (hi-only, 1-MFMA). Partials to Sp slice z.
// ---------------------------------------------------------------------------
__global__ __launch_bounds__(256) void k_scores(
    const u16* __restrict__ Ahi, long lda, long aBS,
    const u16* __restrict__ Bhi, long ldb, long bBS,
    float* __restrict__ Sp)
{
  __shared__ __align__(16) u16 lds[2][16384];   // per buf: PA @0, PB @8192
  const int tid = threadIdx.x;
  const int lane = tid & 63;
  const int wv = tid >> 6;
  const long aOff = (long)blockIdx.y * aBS;
  const long bOff = (long)blockIdx.y * bBS;
  const long cOff = (long)blockIdx.y * 16384 + (long)blockIdx.z * 262144;
  const int kbase = blockIdx.z * 512;

  const int l8 = lane >> 3;
  const int cslot = (lane & 7) ^ l8;
  const int ck = (cslot & 3) * 8;
  const u16* aSrc = Ahi + aOff + (wv * 32 + l8) * lda + ck;
  const u16* bSrc = Bhi + bOff + (wv * 32 + l8) * ldb + ck;
  const int ldsAo = wv * 2048;
  const int ldsBo = 8192 + wv * 2048;

  const int r15 = lane & 15, kq = lane >> 4;
  const int s7 = r15 & 7;
  const int oHi = (kq ^ s7) * 8;
  const int aQ = (wv >> 1) * 64;
  const int bQ = (wv & 1) * 64;

  f32x4 acc[4][4] = {};

#define STAGE(buf, kofs)                                                     \
  {                                                                          \
    const u16* sa = aSrc + (kofs);                                           \
    const u16* sb = bSrc + (kofs);                                           \
    u16* la = &lds[buf][ldsAo];                                              \
    u16* lb = &lds[buf][ldsBo];                                              \
    gload16(sa,            la);        gload16(sa +  8 * lda, la + 512);     \
    gload16(sa + 16 * lda, la + 1024); gload16(sa + 24 * lda, la + 1536);    \
    gload16(sb,            lb);        gload16(sb +  8 * ldb, lb + 512);     \
    gload16(sb + 16 * ldb, lb + 1024); gload16(sb + 24 * ldb, lb + 1536);    \
  }

  STAGE(0, kbase)
  __syncthreads();
  int cur = 0;
  for (int k0 = kbase; k0 < kbase + 512; k0 += 32) {
    if (k0 + 32 < kbase + 512) STAGE(cur ^ 1, k0 + 32)
    const u16* L = &lds[cur][0];
    short8v bh[4];
    #pragma unroll
    for (int j = 0; j < 4; ++j)
      bh[j] = *(const short8v*)&L[8192 + (bQ + j * 16 + r15) * 64 + oHi];
    #pragma unroll
    for (int i = 0; i < 4; ++i) {
      short8v ah = *(const short8v*)&L[(aQ + i * 16 + r15) * 64 + oHi];
      #pragma unroll
      for (int j = 0; j < 4; ++j)
        acc[i][j] = __builtin_amdgcn_mfma_f32_16x16x32_bf16(ah, bh[j], acc[i][j], 0, 0, 0);
    }
    __syncthreads();
    cur ^= 1;
  }
#undef STAGE
  const long row0 = aQ, col0 = bQ;
  #pragma unroll
  for (int i = 0; i < 4; ++i)
    #pragma unroll
    for (int j = 0; j < 4; ++j) {
      long rr = row0 + i * 16 + kq * 4;
      long cc = col0 + j * 16 + r15;
      #pragma unroll
      for (int g = 0; g < 4; ++g)
        Sp[cOff + (rr + g) * 128 + cc] = acc[i][j][g];
    }
}

// ---------------------------------------------------------------------------
// 256x128-tile GEMM, 3-buffer LDS rotation, counted vmcnt(6), 1 barrier/tile.
// ---------------------------------------------------------------------------
template<int NM, bool LOOUT>
__global__ __launch_bounds__(512) void k_gemm256(
    const u16* __restrict__ Ahi, const u16* __restrict__ Alo,
    const u16* __restrict__ Bhi, const u16* __restrict__ Blo,
    u16* __restrict__ Chi, u16* __restrict__ Clo, long ldc, int nTc)
{
  __shared__ __align__(16) u16 lds[73728];   // 3 bufs x (A 16384 | B 8192)
  const int tid = threadIdx.x, lane = tid & 63, wv = tid >> 6;
  const int nwg = gridDim.x;
  const int bid2 = (blockIdx.x & 7) * (nwg >> 3) + (blockIdx.x >> 3);
  const int nT = bid2 % nTc, mT = bid2 / nTc;
  const long aRow0 = (long)mT * 256, bRow0 = (long)nT * 128;

  const int l8 = lane >> 3, cslot = (lane & 7) ^ l8, ck = (cslot & 3) * 8;
  const u16* aSrc = ((cslot < 4) ? Ahi : Alo) + (aRow0 + wv * 32 + l8) * 4096 + ck;
  const u16* bSrc = ((cslot < 4) ? Bhi : Blo) + (bRow0 + wv * 16 + l8) * 4096 + ck;
  const int laO = wv * 2048;            // A: wave stages 32 rows x 64 u16
  const int lbO = 16384 + wv * 1024;    // B: wave stages 16 rows x 64 u16

  const int r15 = lane & 15, kq = lane >> 4, s7 = r15 & 7;
  const int oHi = (kq ^ s7) * 8, oLo = ((4 + kq) ^ s7) * 8;
  const int wm = wv >> 1, wn = wv & 1;
  f32x4 acc[4][4] = {};

#define STG(buf, kofs)                                                       \
  {                                                                          \
    const u16* sa = aSrc + (kofs);                                           \
    const u16* sb = bSrc + (kofs);                                           \
    u16* la = &lds[(buf) * 24576 + laO];                                     \
    u16* lb = &lds[(buf) * 24576 + lbO];                                     \
    gload16(sa,             la);       gload16(sa +  8 * 4096, la + 512);    \
    gload16(sa + 16 * 4096, la + 1024); gload16(sa + 24 * 4096, la + 1536);  \
    gload16(sb,             lb);       gload16(sb +  8 * 4096, lb + 512);    \
  }

  STG(0, 0) STG(1, 32)                  // tiles 0,1 in flight (12 loads)
  for (int kt = 0; kt < 128; ++kt) {
    if (kt < 127) { asm volatile("s_waitcnt vmcnt(6)" ::: "memory"); }
    else          { asm volatile("s_waitcnt vmcnt(0)" ::: "memory"); }
    __builtin_amdgcn_sched_barrier(0);
    __builtin_amdgcn_s_barrier();       // all waves' tile-kt loads complete
    const int bb = (kt % 3) * 24576;
    if (kt < 126) STG((kt + 2) % 3, (kt + 2) * 32)   // 2-deep prefetch
    short8v ah[4], al[4], bh[4], bl[4];
    #pragma unroll
    for (int j = 0; j < 4; ++j) {
      int rb = bb + 16384 + (wn * 64 + j * 16 + r15) * 64;
      bh[j] = *(const short8v*)&lds[rb + oHi];
      if (NM >= 3) bl[j] = *(const short8v*)&lds[rb + oLo];
    }
    #pragma unroll
    for (int i = 0; i < 4; ++i) {
      int ra = bb + (wm * 64 + i * 16 + r15) * 64;
      ah[i] = *(const short8v*)&lds[ra + oHi];
      if (NM >= 2) al[i] = *(const short8v*)&lds[ra + oLo];
    }
    #pragma unroll
    for (int i = 0; i < 4; ++i)
      #pragma unroll
      for (int j = 0; j < 4; ++j) {
        acc[i][j] = __builtin_amdgcn_mfma_f32_16x16x32_bf16(ah[i], bh[j], acc[i][j], 0, 0, 0);
        if (NM >= 3) acc[i][j] = __builtin_amdgcn_mfma_f32_16x16x32_bf16(ah[i], bl[j], acc[i][j], 0, 0, 0);
        if (NM >= 2) acc[i][j] = __builtin_amdgcn_mfma_f32_16x16x32_bf16(al[i], bh[j], acc[i][j], 0, 0, 0);
      }
  }
#undef STG
  // epilogue: split-bf16 store (m89 layout)
  const long row0 = aRow0 + wm * 64;
  const long col0 = bRow0 + wn * 64;
  #pragma unroll
  for (int i = 0; i < 4; ++i)
    #pragma unroll
    for (int j = 0; j < 4; ++j) {
      long rr = row0 + i * 16 + kq * 4;
      long cc = col0 + j * 16 + r15;
      #pragma unroll
      for (int g = 0; g < 4; ++g) {
        float v = acc[i][j][g];
        long idx = (rr + g) * ldc + cc;
        u16 h = f2bf(v);
        Chi[idx] = h;
        if (LOOUT) Clo[idx] = f2bf(v - bf2f(h));
      }
    }
}

// Softmax over strictly-past scores (sums 8 K-slice partials) -> Wx[t][b][t'];
// also zeroes the barrier arrival lines via MALL atomics.
__global__ __launch_bounds__(256) void k_softmax(const float* __restrict__ Sp,
    float* __restrict__ Wx, u32* __restrict__ flags)
{
  if (blockIdx.x == 0) atomswap32(&flags[threadIdx.x * 16], 0);
  const int wv = threadIdx.x >> 6, lane = threadIdx.x & 63;
  const int idx = blockIdx.x * 4 + wv;        // = b*128 + t
  const int b = idx >> 7, t = idx & 127;
  const float* row = &Sp[(long)idx * 128];
  float s0 = 0.f, s1 = 0.f;
  #pragma unroll
  for (int s = 0; s < 8; ++s) {
    s0 += row[s * 262144 + lane];
    s1 += row[s * 262144 + lane + 64];
  }
  float v0 = (lane < t) ? s0 * 0.015625f : -1e30f;
  float v1 = (lane + 64 < t) ? s1 * 0.015625f : -1e30f;
  float m = fmaxf(v0, v1);
  #pragma unroll
  for (int off = 32; off; off >>= 1) m = fmaxf(m, __shfl_xor(m, off));
  float e0 = (lane < t) ? expf(v0 - m) : 0.f;
  float e1 = (lane + 64 < t) ? expf(v1 - m) : 0.f;
  float s = e0 + e1;
  #pragma unroll
  for (int off = 32; off; off >>= 1) s += __shfl_xor(s, off);
  float inv = 1.f / fmaxf(s, 1e-9f);
  float* wr = &Wx[((long)t * 16 + b) * 128];
  wr[lane] = e0 * inv;
  wr[lane + 64] = e1 * inv;
}

// ---------------------------------------------------------------------------
// Persistent phase C. grid 256 = 1 block/CU, 512 thr = 8 waves.
// ONE-HOP barrier: every block atomswaps its own 64B arrival line; every
// block's tid<256 polls ALL 256 lines; waves 4-7 compute next step's
// mix-partial (block-local) DURING the wait.
// ---------------------------------------------------------------------------
__global__ __launch_bounds__(512) void k_phaseC(
    const u16* __restrict__ Wvh, const u16* __restrict__ Wvl,
    const float* __restrict__ Wx,
    const u16* __restrict__ hoh, const u16* __restrict__ hol,
    u16* __restrict__ ring_h,
    float* __restrict__ fdest, int dmode, u32* __restrict__ flags)
{
  __shared__ float VO_lds[128 * 256];        // [t][b*16+col]  128 KB
  __shared__ float vo_w[8][256];
  __shared__ float pctx0[256], pctx1[256];
  const int tid = threadIdx.x;
  const int lane = tid & 63, wv = tid >> 6;
  const int n0 = blockIdx.x * 16;
  const int r15 = lane & 15, kq = lane >> 4;
  const long kb = (long)wv * 512 + kq * 8;   // this lane's K base

  short8v Bh[16], Bl[16];
  {
    const u16* bh = Wvh + (long)(n0 + r15) * 4096 + kb;
    const u16* bl = Wvl + (long)(n0 + r15) * 4096 + kb;
    #pragma unroll
    for (int c = 0; c < 16; ++c) {
      Bh[c] = *(const short8v*)(bh + c * 32);
      Bl[c] = *(const short8v*)(bl + c * 32);
    }
    #pragma unroll
    for (int c = 0; c < 16; ++c) {
      asm volatile("" : "+v"(Bh[c]));
      asm volatile("" : "+v"(Bl[c]));
    }
  }
  const long abase = (long)r15 * 4096 + kb;  // A-frag base (row = batch r15)
  const int b8 = tid >> 4, col8 = tid & 15;  // (b, col) for tid<256

  // 1-hop barrier + overlapped pctx for target iter T (covers tp < T with
  // weight row (T+1)). Arrive -> waves4-7 pctx / waves0-3 poll -> join.
#define GBAR_PCTX(n, T)                                                      \
  {                                                                          \
    asm volatile("s_waitcnt vmcnt(0)" ::: "memory");                         \
    __syncthreads();                                                         \
    if (tid == 0) atomswap32(&flags[(u32)blockIdx.x * 16], (n));             \
    if (tid >= 256) {                                                        \
      const int id = tid - 256;                                              \
      const int bm = id >> 4;                                                \
      const float* wrowm = &Wx[((long)((T) + 1) * 16 + bm) * 128];           \
      float c0 = 0.f, c1 = 0.f;                                              \
      int tp = 0;                                                            \
      for (; tp + 1 < (T); tp += 2) {                                        \
        c0 += wrowm[tp] * VO_lds[tp * 256 + id];                             \
        c1 += wrowm[tp + 1] * VO_lds[(tp + 1) * 256 + id];                   \
      }                                                                      \
      if (tp < (T)) c0 += wrowm[tp] * VO_lds[tp * 256 + id];                 \
      pctx0[id] = c0; pctx1[id] = c1;                                        \
    } else {                                                                 \
      while (ldsc32(&flags[tid * 16]) < (n)) __builtin_amdgcn_s_sleep(1);    \
    }                                                                        \
    __syncthreads();                                                         \
  }

#define RING_STORE(slot, oval)                                               \
  {                                                                          \
    u16 hh_ = f2bf(oval);                                                    \
    u32 vh_ = hh_;                                                           \
    u32 ph_ = (u32)__shfl_xor((int)vh_, 1);                                  \
    if (!(col8 & 1)) {                                                       \
      long oi_ = (long)(slot) * 65536 + (long)b8 * 4096 + n0 + col8;         \
      atomswap32((u32*)&ring_h[oi_], vh_ | (ph_ << 16));                     \
    }                                                                        \
  }

  if (tid < 256) {
    float v = tanhf(bf2f(hoh[(long)b8 * 12288 + n0 + col8])
                  + bf2f(hol[(long)b8 * 12288 + n0 + col8]));
    RING_STORE(0, v)
    if (dmode == 0) fdest[(long)b8 * 4096 + n0 + col8] = v;
    else            fdest[(long)b8 * 128 * 4096 + n0 + col8] = v;
  }
  u32 bn = 1;
  GBAR_PCTX(bn, 0) ++bn;

#define MF(a, b) acc = __builtin_amdgcn_mfma_f32_16x16x32_bf16(a, b, acc, 0, 0, 0);

  for (int t = 0; t < 127; ++t) {
    const u16* ph = ring_h + (long)t * 65536 + abase;   // plain cached loads
    short8v xh[16];
    #pragma unroll
    for (int c = 0; c < 16; ++c) xh[c] = *(const short8v*)(ph + c * 32);
    f32x4 acc = {0.f, 0.f, 0.f, 0.f};
    #pragma unroll
    for (int c = 0; c < 16; ++c) { MF(xh[c], Bh[c]) MF(xh[c], Bl[c]) }
    #pragma unroll
    for (int g = 0; g < 4; ++g)
      vo_w[wv][(kq * 4 + g) * 16 + r15] = acc[g];
    __syncthreads();
    if (tid < 256) {
      float v = vo_w[0][tid] + vo_w[1][tid] + vo_w[2][tid] + vo_w[3][tid]
              + vo_w[4][tid] + vo_w[5][tid] + vo_w[6][tid] + vo_w[7][tid];
      VO_lds[t * 256 + tid] = v;
      const float* wrow = &Wx[((long)(t + 1) * 16 + b8) * 128];
      long hix = ((long)(t + 1) * 16 + b8) * 12288 + n0 + col8;
      float o = tanhf(bf2f(hoh[hix]) + bf2f(hol[hix])
                      + pctx0[tid] + pctx1[tid] + wrow[t] * v);
      RING_STORE(t + 1, o)
      if (dmode == 0) fdest[((long)(t + 1) * 16 + b8) * 4096 + n0 + col8] = o;
      else            fdest[((long)b8 * 128 + (t + 1)) * 4096 + n0 + col8] = o;
    }
    if (t < 126) { GBAR_PCTX(bn, t + 1) ++bn; }
  }
#undef GBAR_PCTX
#undef RING_STORE
#undef MF
}

// ---------------------------------------------------------------------------
extern "C" void kernel_launch(void* const* d_in, const int* in_sizes, int n_in,
                              void* d_out, int out_size, void* d_ws, size_t ws_size,
                              hipStream_t stream)
{
  (void)in_sizes; (void)n_in; (void)out_size;
  if (ws_size < 472383488UL) return;  // need ~451 MiB scratch
  char* ws = (char*)d_ws;
  u16* WT_hi = (u16*)(ws + 0UL);               // 96 MB
  u16* WT_lo = (u16*)(ws + 100663296UL);       // 96 MB
  u16* WV_hi = (u16*)(ws + 33554432UL);        // reuses dead WT rows
  u16* WV_lo = (u16*)(ws + 134217728UL);
  u16* QKOh  = (u16*)(ws + 201326592UL);       // [2048][12288] hi (48 MB)
  u16* QKOl  = (u16*)(ws + 251658240UL);       // lo (HO cols only used)
  u16* Wvo_hi = (u16*)(ws + 301989888UL);      // 32 MB (reused per layer)
  u16* Wvo_lo = (u16*)(ws + 335544320UL);      // 32 MB
  u16* Hs_hi = (u16*)(ws + 369098752UL);       // 16 MB
  u16* Hs_lo = (u16*)(ws + 385875968UL);
  float* Wmx  = (float*)(ws + 403701760UL);    // 1 MB
  float* OUT0 = (float*)(ws + 404754432UL);    // 32 MB
  u16* ring_h = (u16*)(ws + 438308864UL);      // 16 MB: 128 x [16][4096]
  float* Sp   = (float*)(ws + 455086080UL);    // 8 MB: 8 K-slices x 16x128x128
  u32* flg    = (u32*)(ws + 471859200UL);      // 16 KB (256 x 64B lines)
  float* dout = (float*)d_out;
  const float* x_flat = (const float*)d_in[0];

  for (int l = 0; l < 2; ++l) {
    const float* cw = (const float*)d_in[1 + l * 6];
    const float* cb = (const float*)d_in[2 + l * 6];
    const float* wq = (const float*)d_in[3 + l * 6];
    const float* wk = (const float*)d_in[4 + l * 6];
    const float* wv = (const float*)d_in[5 + l * 6];
    const float* wo = (const float*)d_in[6 + l * 6];
    const int cin = (l == 0) ? 17 : 32;

    // Phase A: ConvLSTM recurrence -> split h_vec rows
    hipLaunchKernelGGL(k_conv, dim3(256), dim3(256), 0, stream,
        cin, l, (l == 0) ? x_flat : OUT0, cw, cb, Hs_hi, Hs_lo);

    // Phase B1: fused transposes, then QK (1-MFMA hi) + HO (3-MFMA split)
    hipLaunchKernelGGL(k_tsplit3, dim3(16384, 3), dim3(256), 0, stream,
        wq, wk, wo, WT_hi, WT_lo);
    hipLaunchKernelGGL((k_gemm256<1, false>), dim3(512), dim3(512), 0, stream,
        Hs_hi, Hs_hi, WT_hi, WT_hi, QKOh, (u16*)nullptr, 12288L, 64);
    hipLaunchKernelGGL((k_gemm256<3, true>), dim3(256), dim3(512), 0, stream,
        Hs_hi, Hs_lo, WT_hi + 33554432UL, WT_lo + 33554432UL,
        QKOh + 8192, QKOl + 8192, 12288L, 32);

    // Phase B2: composite Wvo^T = (wv @ wo_c)^T  (2-MFMA: A split, B hi)
    hipLaunchKernelGGL(k_prepB2, dim3(16384, 2), dim3(256), 0, stream,
        wo + 16777216UL, wv, WT_hi, WT_lo, WV_hi, WV_lo);
    hipLaunchKernelGGL((k_gemm256<2, true>), dim3(512), dim3(512), 0, stream,
        WT_hi, WT_lo, WV_hi, WV_hi, Wvo_hi, Wvo_lo, 4096L, 32);

    // Scores, K-split x8: S[b][t][t'] partials then summed in softmax
    hipLaunchKernelGGL(k_scores, dim3(1, 16, 8), dim3(256), 0, stream,
        QKOh, 12288L, 196608L, QKOh + 4096, 12288L, 196608L, Sp);
    hipLaunchKernelGGL(k_softmax, dim3(512), dim3(256), 0, stream, Sp, Wmx, flg);

    // Phase C: ONE persistent kernel (1-hop barrier, overlapped pctx)
    hipLaunchKernelGGL(k_phaseC, dim3(256), dim3(512), 0, stream,
        Wvo_hi, Wvo_lo, Wmx, QKOh + 8192, QKOl + 8192,
        ring_h, (l == 0) ? OUT0 : dout, l, flg);
  }
}

// Round 15
// 3893.258 us; speedup vs baseline: 1.7458x; 1.0487x over previous
//
#include <hip/hip_runtime.h>

typedef unsigned short u16;
typedef unsigned int u32;
typedef __attribute__((ext_vector_type(8))) short short8v;   // 8 bf16 (4 VGPR) MFMA frag
typedef __attribute__((ext_vector_type(4))) float f32x4;     // MFMA acc
typedef __attribute__((ext_vector_type(8))) u16 ush8;
typedef __attribute__((ext_vector_type(4))) u16 ush4;

__device__ __forceinline__ u16 f2bf(float x) {               // RNE f32->bf16
  u32 u = __builtin_bit_cast(u32, x);
  return (u16)((u + 0x7FFFu + ((u >> 16) & 1u)) >> 16);
}
__device__ __forceinline__ float bf2f(u16 h) {
  u32 u = ((u32)h) << 16;
  return __builtin_bit_cast(float, u);
}
__device__ __forceinline__ float sigm(float x) { return 1.f / (1.f + expf(-x)); }

typedef const __attribute__((address_space(1))) void gv_t;
typedef __attribute__((address_space(3))) void lv_t;
__device__ __forceinline__ void gload16(const void* g, void* l) {
  __builtin_amdgcn_global_load_lds((gv_t*)g, (lv_t*)l, 16, 0, 0);
}

// --- device-coherent access helpers -----------------------------------------
__device__ __forceinline__ u32 ldsc32(const u32* p) {        // bypass L1/L2
  u32 v;
  asm volatile("global_load_dword %0, %1, off sc0 sc1\n\ts_waitcnt vmcnt(0)"
               : "=v"(v) : "v"(p) : "memory");
  return v;
}
// MALL coherent store: device-scope atomic swap, NO-RETURN form
__device__ __forceinline__ void atomswap32(u32* p, u32 v) {
  asm volatile("global_atomic_swap %0, %1, off" :: "v"(p), "v"(v) : "memory");
}

// ---------------------------------------------------------------------------
// k_prep: ONE dispatch for conv recurrence + all 5 weight transforms.
//  blocks [0,256):        ConvLSTM recurrence (launched first, longest)
//  blocks [256,49408):    transpose+split wq|wk|wo_h -> WT_hi (+WTh_lo for wo_h)
//  blocks [49408,65792):  transpose+split wo_c -> WTc_hi/lo
//  blocks [65792,82176):  elementwise split wv -> WV_hi (hi only)
// ---------------------------------------------------------------------------
__global__ __launch_bounds__(256) void k_prep(int cin, int xmode,
    const float* __restrict__ xin,
    const float* __restrict__ cw, const float* __restrict__ cb,
    const float* __restrict__ wq, const float* __restrict__ wk,
    const float* __restrict__ wo, const float* __restrict__ wv,
    u16* __restrict__ hhi, u16* __restrict__ hlo,
    u16* __restrict__ WT_hi, u16* __restrict__ WTh_lo,
    u16* __restrict__ WTc_hi, u16* __restrict__ WTc_lo,
    u16* __restrict__ WV_hi)
{
  __shared__ __align__(16) float smem[6912];   // conv: zb|wb|bb; transpose: tb
  const int bx = blockIdx.x;
  const int tid = threadIdx.x;

  if (bx < 256) {                     // ---- ConvLSTM ----
    float* zb = smem;                 // 32*18 = 576
    float* wb = smem + 576;           // 6144
    float* bb = smem + 6720;          // 64
    const int b = bx >> 4, r = bx & 15;
    const int ch = tid >> 4, col = tid & 15;
    const int cx = cin - 16;
    for (int i = tid; i < 64 * cin * 3; i += 256) {
      int tap = i % 3, tmp = i / 3;
      int ic = tmp % cin, oc = tmp / cin;
      wb[(((oc & 15) * cin + ic) * 3 + tap) * 4 + (oc >> 4)] = cw[i];
    }
    if (tid < 64) bb[tid] = cb[tid];
    for (int i = tid; i < cin * 18; i += 256) zb[i] = 0.f;
    __syncthreads();
    float h = 0.f, c = 0.f;
    const int lane = tid & 63;
    for (int t = 0; t < 128; ++t) {
      if (xmode == 0) {
        if (ch == 0) zb[col + 1] = xin[((long)b * 128 + t) * 256 + r * 16 + col];
      } else {
        zb[ch * 18 + col + 1] = xin[((long)t * 16 + b) * 4096 + r * 256 + ch * 16 + col];
      }
      zb[(cx + ch) * 18 + col + 1] = h;
      __syncthreads();
      float a0 = bb[ch], a1 = bb[16 + ch], a2 = bb[32 + ch], a3 = bb[48 + ch];
      for (int ic = 0; ic < cin; ++ic) {
        float z1 = zb[ic * 18 + col + 1];
        float z0 = __shfl(z1, lane - 1);
        float z2 = __shfl(z1, lane + 1);
        if (col == 0) z0 = 0.f;
        if (col == 15) z2 = 0.f;
        const float4* wp = (const float4*)&wb[(ch * cin + ic) * 12];
        float4 w0 = wp[0], w1 = wp[1], w2 = wp[2];
        a0 += z0 * w0.x + z1 * w1.x + z2 * w2.x;
        a1 += z0 * w0.y + z1 * w1.y + z2 * w2.y;
        a2 += z0 * w0.z + z1 * w1.z + z2 * w2.z;
        a3 += z0 * w0.w + z1 * w1.w + z2 * w2.w;
      }
      __syncthreads();
      c = sigm(a1) * c + sigm(a0) * tanhf(a2);   // i,f,g,o gate order
      h = sigm(a3) * tanhf(c);
      long idx = ((long)t * 16 + b) * 4096 + (long)r * 256 + ch * 16 + col;
      u16 hh = f2bf(h);
      hhi[idx] = hh;
      hlo[idx] = f2bf(h - bf2f(hh));
    }
    return;
  }

  if (bx >= 65792) {                  // ---- wv split (hi only) ----
    long i = ((long)(bx - 65792) * 256 + tid) * 4;
    const float4 v = *(const float4*)&wv[i];
    ush4 hv = {f2bf(v.x), f2bf(v.y), f2bf(v.z), f2bf(v.w)};
    *(ush4*)&WV_hi[i] = hv;
    return;
  }

  // ---- transposes ----
  float (*tb)[33] = (float(*)[33])smem;
  const float* W;
  u16 *hid, *lod;
  int writeLo;
  int tile;
  if (bx < 49408) {
    int t = bx - 256;
    int y = t >> 14;                  // 0:wq 1:wk 2:wo_h
    tile = t & 16383;
    W = (y == 0) ? wq : (y == 1) ? wk : wo;
    hid = WT_hi + (unsigned long)y * 16777216UL;
    lod = WTh_lo;
    writeLo = (y == 2);
  } else {
    tile = bx - 49408;
    W = wo + 16777216UL;              // wo_c
    hid = WTc_hi;
    lod = WTc_lo;
    writeLo = 1;
  }
  const int tn = tile & 127, tk = tile >> 7;
  const int n0 = tn * 32, k0 = tk * 32;
  const int lr = tid >> 5, lc = tid & 31;
  #pragma unroll
  for (int i = 0; i < 4; ++i)
    tb[lr + i * 8][lc] = W[(long)(k0 + lr + i * 8) * 4096 + n0 + lc];
  __syncthreads();
  #pragma unroll
  for (int i = 0; i < 4; ++i) {
    int n = lr + i * 8;
    float v = tb[lc][n];
    long idx = (long)(n0 + n) * 4096 + k0 + lc;
    u16 h = f2bf(v);
    hid[idx] = h;
    if (writeLo) lod[idx] = f2bf(v - bf2f(h));
  }
}

// ---------------------------------------------------------------------------
// 256x128-tile GEMM core (device fn): 3-buffer LDS rotation, counted
// vmcnt(6), 1 barrier/tile. NM = #MFMAs/pair; LOOUT: write split-lo C with
// its own ldclo. nwg divisible by 8 (XCD swizzle).
// ---------------------------------------------------------------------------
template<int NM, bool LOOUT>
__device__ __forceinline__ void gemm_core(u16* lds, int bid, int nwg,
    const u16* __restrict__ Ahi, const u16* __restrict__ Alo,
    const u16* __restrict__ Bhi, const u16* __restrict__ Blo,
    u16* __restrict__ Chi, u16* __restrict__ Clo,
    long ldc, long ldclo, int nTc)
{
  const int tid = threadIdx.x, lane = tid & 63, wv = tid >> 6;
  const int bid2 = (bid & 7) * (nwg >> 3) + (bid >> 3);
  const int nT = bid2 % nTc, mT = bid2 / nTc;
  const long aRow0 = (long)mT * 256, bRow0 = (long)nT * 128;

  const int l8 = lane >> 3, cslot = (lane & 7) ^ l8, ck = (cslot & 3) * 8;
  const u16* aSrc = ((cslot < 4) ? Ahi : Alo) + (aRow0 + wv * 32 + l8) * 4096 + ck;
  const u16* bSrc = ((cslot < 4) ? Bhi : Blo) + (bRow0 + wv * 16 + l8) * 4096 + ck;
  const int laO = wv * 2048;            // A: wave stages 32 rows x 64 u16
  const int lbO = 16384 + wv * 1024;    // B: wave stages 16 rows x 64 u16

  const int r15 = lane & 15, kq = lane >> 4, s7 = r15 & 7;
  const int oHi = (kq ^ s7) * 8, oLo = ((4 + kq) ^ s7) * 8;
  const int wm = wv >> 1, wn = wv & 1;
  f32x4 acc[4][4] = {};

#define STG(buf, kofs)                                                       \
  {                                                                          \
    const u16* sa = aSrc + (kofs);                                           \
    const u16* sb = bSrc + (kofs);                                           \
    u16* la = &lds[(buf) * 24576 + laO];                                     \
    u16* lb = &lds[(buf) * 24576 + lbO];                                     \
    gload16(sa,             la);       gload16(sa +  8 * 4096, la + 512);    \
    gload16(sa + 16 * 4096, la + 1024); gload16(sa + 24 * 4096, la + 1536);  \
    gload16(sb,             lb);       gload16(sb +  8 * 4096, lb + 512);    \
  }

  STG(0, 0) STG(1, 32)                  // tiles 0,1 in flight (12 loads)
  for (int kt = 0; kt < 128; ++kt) {
    if (kt < 127) { asm volatile("s_waitcnt vmcnt(6)" ::: "memory"); }
    else          { asm volatile("s_waitcnt vmcnt(0)" ::: "memory"); }
    __builtin_amdgcn_sched_barrier(0);
    __builtin_amdgcn_s_barrier();       // all waves' tile-kt loads complete
    const int bb = (kt % 3) * 24576;
    if (kt < 126) STG((kt + 2) % 3, (kt + 2) * 32)   // 2-deep prefetch
    short8v ah[4], al[4], bh[4], bl[4];
    #pragma unroll
    for (int j = 0; j < 4; ++j) {
      int rb = bb + 16384 + (wn * 64 + j * 16 + r15) * 64;
      bh[j] = *(const short8v*)&lds[rb + oHi];
      if (NM >= 3) bl[j] = *(const short8v*)&lds[rb + oLo];
    }
    #pragma unroll
    for (int i = 0; i < 4; ++i) {
      int ra = bb + (wm * 64 + i * 16 + r15) * 64;
      ah[i] = *(const short8v*)&lds[ra + oHi];
      if (NM >= 2) al[i] = *(const short8v*)&lds[ra + oLo];
    }
    #pragma unroll
    for (int i = 0; i < 4; ++i)
      #pragma unroll
      for (int j = 0; j < 4; ++j) {
        acc[i][j] = __builtin_amdgcn_mfma_f32_16x16x32_bf16(ah[i], bh[j], acc[i][j], 0, 0, 0);
        if (NM >= 3) acc[i][j] = __builtin_amdgcn_mfma_f32_16x16x32_bf16(ah[i], bl[j], acc[i][j], 0, 0, 0);
        if (NM >= 2) acc[i][j] = __builtin_amdgcn_mfma_f32_16x16x32_bf16(al[i], bh[j], acc[i][j], 0, 0, 0);
      }
  }
#undef STG
  // epilogue: split-bf16 store (m89 layout)
  const long row0 = aRow0 + wm * 64;
  const long col0 = bRow0 + wn * 64;
  #pragma unroll
  for (int i = 0; i < 4; ++i)
    #pragma unroll
    for (int j = 0; j < 4; ++j) {
      long rr = row0 + i * 16 + kq * 4;
      long cc = col0 + j * 16 + r15;
      #pragma unroll
      for (int g = 0; g < 4; ++g) {
        float v = acc[i][j][g];
        u16 h = f2bf(v);
        Chi[(rr + g) * ldc + cc] = h;
        if (LOOUT) Clo[(rr + g) * ldclo + cc] = f2bf(v - bf2f(h));
      }
    }
}

// Merged phase-B GEMMs: [0,512) QK (NM=1 hi-only), [512,768) HO (NM=3),
// [768,1280) Wvo (NM=2). 1280 blocks = 5 full CU rounds.
__global__ __launch_bounds__(512) void k_gemmB(
    const u16* __restrict__ Hs_hi, const u16* __restrict__ Hs_lo,
    const u16* __restrict__ WT_hi, const u16* __restrict__ WTh_lo,
    const u16* __restrict__ WTc_hi, const u16* __restrict__ WTc_lo,
    const u16* __restrict__ WV_hi,
    u16* __restrict__ QKOh, u16* __restrict__ HOlo,
    u16* __restrict__ Wvo_hi, u16* __restrict__ Wvo_lo)
{
  __shared__ __align__(16) u16 lds[73728];   // 3 bufs x (A 16384 | B 8192)
  const int bx = blockIdx.x;
  if (bx < 512) {
    gemm_core<1, false>(lds, bx, 512, Hs_hi, Hs_hi, WT_hi, WT_hi,
                        QKOh, (u16*)nullptr, 12288L, 0L, 64);
  } else if (bx < 768) {
    gemm_core<3, true>(lds, bx - 512, 256, Hs_hi, Hs_lo,
                       WT_hi + 33554432UL, WTh_lo,
                       QKOh + 8192, HOlo, 12288L, 4096L, 32);
  } else {
    gemm_core<2, true>(lds, bx - 768, 512, WTc_hi, WTc_lo, WV_hi, WV_hi,
                       Wvo_hi, Wvo_lo, 4096L, 4096L, 32);
  }
}

// ---------------------------------------------------------------------------
// Scores GEMM, K-split x8 (hi-only, 1-MFMA). Partials to Sp slice z.
// ---------------------------------------------------------------------------
__global__ __launch_bounds__(256) void k_scores(
    const u16* __restrict__ Ahi, long lda, long aBS,
    const u16* __restrict__ Bhi, long ldb, long bBS,
    float* __restrict__ Sp)
{
  __shared__ __align__(16) u16 lds[2][16384];   // per buf: PA @0, PB @8192
  const int tid = threadIdx.x;
  const int lane = tid & 63;
  const int wv = tid >> 6;
  const long aOff = (long)blockIdx.y * aBS;
  const long bOff = (long)blockIdx.y * bBS;
  const long cOff = (long)blockIdx.y * 16384 + (long)blockIdx.z * 262144;
  const int kbase = blockIdx.z * 512;

  const int l8 = lane >> 3;
  const int cslot = (lane & 7) ^ l8;
  const int ck = (cslot & 3) * 8;
  const u16* aSrc = Ahi + aOff + (wv * 32 + l8) * lda + ck;
  const u16* bSrc = Bhi + bOff + (wv * 32 + l8) * ldb + ck;
  const int ldsAo = wv * 2048;
  const int ldsBo = 8192 + wv * 2048;

  const int r15 = lane & 15, kq = lane >> 4;
  const int s7 = r15 & 7;
  const int oHi = (kq ^ s7) * 8;
  const int aQ = (wv >> 1) * 64;
  const int bQ = (wv & 1) * 64;

  f32x4 acc[4][4] = {};

#define STAGE(buf, kofs)                                                     \
  {                                                                          \
    const u16* sa = aSrc + (kofs);                                           \
    const u16* sb = bSrc + (kofs);                                           \
    u16* la = &lds[buf][ldsAo];                                              \
    u16* lb = &lds[buf][ldsBo];                                              \
    gload16(sa,            la);        gload16(sa +  8 * lda, la + 512);     \
    gload16(sa + 16 * lda, la + 1024); gload16(sa + 24 * lda, la + 1536);    \
    gload16(sb,            lb);        gload16(sb +  8 * ldb, lb + 512);     \
    gload16(sb + 16 * ldb, lb + 1024); gload16(sb + 24 * ldb, lb + 1536);    \
  }

  STAGE(0, kbase)
  __syncthreads();
  int cur = 0;
  for (int k0 = kbase; k0 < kbase + 512; k0 += 32) {
    if (k0 + 32 < kbase + 512) STAGE(cur ^ 1, k0 + 32)
    const u16* L = &lds[cur][0];
    short8v bh[4];
    #pragma unroll
    for (int j = 0; j < 4; ++j)
      bh[j] = *(const short8v*)&L[8192 + (bQ + j * 16 + r15) * 64 + oHi];
    #pragma unroll
    for (int i = 0; i < 4; ++i) {
      short8v ah = *(const short8v*)&L[(aQ + i * 16 + r15) * 64 + oHi];
      #pragma unroll
      for (int j = 0; j < 4; ++j)
        acc[i][j] = __builtin_amdgcn_mfma_f32_16x16x32_bf16(ah, bh[j], acc[i][j], 0, 0, 0);
    }
    __syncthreads();
    cur ^= 1;
  }
#undef STAGE
  const long row0 = aQ, col0 = bQ;
  #pragma unroll
  for (int i = 0; i < 4; ++i)
    #pragma unroll
    for (int j = 0; j < 4; ++j) {
      long rr = row0 + i * 16 + kq * 4;
      long cc = col0 + j * 16 + r15;
      #pragma unroll
      for (int g = 0; g < 4; ++g)
        Sp[cOff + (rr + g) * 128 + cc] = acc[i][j][g];
    }
}

// Softmax over strictly-past scores (sums 8 K-slice partials) -> Wx[t][b][t'];
// also zeroes the barrier arrival lines via MALL atomics.
__global__ __launch_bounds__(256) void k_softmax(const float* __restrict__ Sp,
    float* __restrict__ Wx, u32* __restrict__ flags)
{
  if (blockIdx.x == 0) atomswap32(&flags[threadIdx.x * 16], 0);
  const int wv = threadIdx.x >> 6, lane = threadIdx.x & 63;
  const int idx = blockIdx.x * 4 + wv;        // = b*128 + t
  const int b = idx >> 7, t = idx & 127;
  const float* row = &Sp[(long)idx * 128];
  float s0 = 0.f, s1 = 0.f;
  #pragma unroll
  for (int s = 0; s < 8; ++s) {
    s0 += row[s * 262144 + lane];
    s1 += row[s * 262144 + lane + 64];
  }
  float v0 = (lane < t) ? s0 * 0.015625f : -1e30f;
  float v1 = (lane + 64 < t) ? s1 * 0.015625f : -1e30f;
  float m = fmaxf(v0, v1);
  #pragma unroll
  for (int off = 32; off; off >>= 1) m = fmaxf(m, __shfl_xor(m, off));
  float e0 = (lane < t) ? expf(v0 - m) : 0.f;
  float e1 = (lane + 64 < t) ? expf(v1 - m) : 0.f;
  float s = e0 + e1;
  #pragma unroll
  for (int off = 32; off; off >>= 1) s += __shfl_xor(s, off);
  float inv = 1.f / fmaxf(s, 1e-9f);
  float* wr = &Wx[((long)t * 16 + b) * 128];
  wr[lane] = e0 * inv;
  wr[lane + 64] = e1 * inv;
}

// ---------------------------------------------------------------------------
// Persistent phase C (unchanged structure from r14; HO-lo stride now 4096).
// ---------------------------------------------------------------------------
__global__ __launch_bounds__(512) void k_phaseC(
    const u16* __restrict__ Wvh, const u16* __restrict__ Wvl,
    const float* __restrict__ Wx,
    const u16* __restrict__ hoh, const u16* __restrict__ hol,
    u16* __restrict__ ring_h,
    float* __restrict__ fdest, int dmode, u32* __restrict__ flags)
{
  __shared__ float VO_lds[128 * 256];        // [t][b*16+col]  128 KB
  __shared__ float vo_w[8][256];
  __shared__ float pctx0[256], pctx1[256];
  const int tid = threadIdx.x;
  const int lane = tid & 63, wv = tid >> 6;
  const int n0 = blockIdx.x * 16;
  const int r15 = lane & 15, kq = lane >> 4;
  const long kb = (long)wv * 512 + kq * 8;   // this lane's K base

  short8v Bh[16], Bl[16];
  {
    const u16* bh = Wvh + (long)(n0 + r15) * 4096 + kb;
    const u16* bl = Wvl + (long)(n0 + r15) * 4096 + kb;
    #pragma unroll
    for (int c = 0; c < 16; ++c) {
      Bh[c] = *(const short8v*)(bh + c * 32);
      Bl[c] = *(const short8v*)(bl + c * 32);
    }
    #pragma unroll
    for (int c = 0; c < 16; ++c) {
      asm volatile("" : "+v"(Bh[c]));
      asm volatile("" : "+v"(Bl[c]));
    }
  }
  const long abase = (long)r15 * 4096 + kb;  // A-frag base (row = batch r15)
  const int b8 = tid >> 4, col8 = tid & 15;  // (b, col) for tid<256

#define GBAR_PCTX(n, T)                                                      \
  {                                                                          \
    asm volatile("s_waitcnt vmcnt(0)" ::: "memory");                         \
    __syncthreads();                                                         \
    if (tid == 0) atomswap32(&flags[(u32)blockIdx.x * 16], (n));             \
    if (tid >= 256) {                                                        \
      const int id = tid - 256;                                              \
      const int bm = id >> 4;                                                \
      const float* wrowm = &Wx[((long)((T) + 1) * 16 + bm) * 128];           \
      float c0 = 0.f, c1 = 0.f;                                              \
      int tp = 0;                                                            \
      for (; tp + 1 < (T); tp += 2) {                                        \
        c0 += wrowm[tp] * VO_lds[tp * 256 + id];                             \
        c1 += wrowm[tp + 1] * VO_lds[(tp + 1) * 256 + id];                   \
      }                                                                      \
      if (tp < (T)) c0 += wrowm[tp] * VO_lds[tp * 256 + id];                 \
      pctx0[id] = c0; pctx1[id] = c1;                                        \
    } else {                                                                 \
      while (ldsc32(&flags[tid * 16]) < (n)) __builtin_amdgcn_s_sleep(1);    \
    }                                                                        \
    __syncthreads();                                                         \
  }

#define RING_STORE(slot, oval)                                               \
  {                                                                          \
    u16 hh_ = f2bf(oval);                                                    \
    u32 vh_ = hh_;                                                           \
    u32 ph_ = (u32)__shfl_xor((int)vh_, 1);                                  \
    if (!(col8 & 1)) {                                                       \
      long oi_ = (long)(slot) * 65536 + (long)b8 * 4096 + n0 + col8;         \
      atomswap32((u32*)&ring_h[oi_], vh_ | (ph_ << 16));                     \
    }                                                                        \
  }

  if (tid < 256) {
    float v = tanhf(bf2f(hoh[(long)b8 * 12288 + n0 + col8])
                  + bf2f(hol[(long)b8 * 4096 + n0 + col8]));
    RING_STORE(0, v)
    if (dmode == 0) fdest[(long)b8 * 4096 + n0 + col8] = v;
    else            fdest[(long)b8 * 128 * 4096 + n0 + col8] = v;
  }
  u32 bn = 1;
  GBAR_PCTX(bn, 0) ++bn;

#define MF(a, b) acc = __builtin_amdgcn_mfma_f32_16x16x32_bf16(a, b, acc, 0, 0, 0);

  for (int t = 0; t < 127; ++t) {
    const u16* ph = ring_h + (long)t * 65536 + abase;   // plain cached loads
    short8v xh[16];
    #pragma unroll
    for (int c = 0; c < 16; ++c) xh[c] = *(const short8v*)(ph + c * 32);
    f32x4 acc = {0.f, 0.f, 0.f, 0.f};
    #pragma unroll
    for (int c = 0; c < 16; ++c) { MF(xh[c], Bh[c]) MF(xh[c], Bl[c]) }
    #pragma unroll
    for (int g = 0; g < 4; ++g)
      vo_w[wv][(kq * 4 + g) * 16 + r15] = acc[g];
    __syncthreads();
    if (tid < 256) {
      float v = vo_w[0][tid] + vo_w[1][tid] + vo_w[2][tid] + vo_w[3][tid]
              + vo_w[4][tid] + vo_w[5][tid] + vo_w[6][tid] + vo_w[7][tid];
      VO_lds[t * 256 + tid] = v;
      const float* wrow = &Wx[((long)(t + 1) * 16 + b8) * 128];
      float ho = bf2f(hoh[((long)(t + 1) * 16 + b8) * 12288 + n0 + col8])
               + bf2f(hol[((long)(t + 1) * 16 + b8) * 4096 + n0 + col8]);
      float o = tanhf(ho + pctx0[tid] + pctx1[tid] + wrow[t] * v);
      RING_STORE(t + 1, o)
      if (dmode == 0) fdest[((long)(t + 1) * 16 + b8) * 4096 + n0 + col8] = o;
      else            fdest[((long)b8 * 128 + (t + 1)) * 4096 + n0 + col8] = o;
    }
    if (t < 126) { GBAR_PCTX(bn, t + 1) ++bn; }
  }
#undef GBAR_PCTX
#undef RING_STORE
#undef MF
}

// ---------------------------------------------------------------------------
extern "C" void kernel_launch(void* const* d_in, const int* in_sizes, int n_in,
                              void* d_out, int out_size, void* d_ws, size_t ws_size,
                              hipStream_t stream)
{
  (void)in_sizes; (void)n_in; (void)out_size;
  if (ws_size < 454049792UL) return;
  char* ws = (char*)d_ws;
  u16* WT_hi  = (u16*)(ws + 0UL);              // 96 MB: wq^T|wk^T|wo_h^T
  u16* WTh_lo = (u16*)(ws + 100663296UL);      // 32 MB: wo_h^T lo
  u16* WTc_hi = (u16*)(ws + 134217728UL);      // 32 MB: wo_c^T hi
  u16* WTc_lo = (u16*)(ws + 167772160UL);      // 32 MB: wo_c^T lo
  u16* WV_hi  = (u16*)(ws + 201326592UL);      // 32 MB: wv hi
  u16* QKOh   = (u16*)(ws + 234881024UL);      // 48 MB: [2048][12288] hi
  u16* HOlo   = (u16*)(ws + 285212672UL);      // 16 MB: [2048][4096] ho lo
  u16* Wvo_hi = (u16*)(ws + 301989888UL);      // 32 MB
  u16* Wvo_lo = (u16*)(ws + 335544320UL);      // 32 MB
  u16* Hs_hi  = (u16*)(ws + 369098752UL);      // 16 MB
  u16* Hs_lo  = (u16*)(ws + 385875968UL);      // 16 MB
  float* Wmx  = (float*)(ws + 402653184UL);    // 1 MB
  u16* ring_h = (u16*)(ws + 403701760UL);      // 16 MB: 128 x [16][4096]
  float* OUT0 = (float*)(ws + 420478976UL);    // 32 MB (Sp aliases 1st 8 MB)
  float* Sp   = (float*)(ws + 420478976UL);    // alias (lifetime-checked)
  u32* flg    = (u32*)(ws + 454033408UL);      // 16 KB (256 x 64B lines)
  float* dout = (float*)d_out;
  const float* x_flat = (const float*)d_in[0];

  for (int l = 0; l < 2; ++l) {
    const float* cw = (const float*)d_in[1 + l * 6];
    const float* cb = (const float*)d_in[2 + l * 6];
    const float* wq = (const float*)d_in[3 + l * 6];
    const float* wk = (const float*)d_in[4 + l * 6];
    const float* wv = (const float*)d_in[5 + l * 6];
    const float* wo = (const float*)d_in[6 + l * 6];
    const int cin = (l == 0) ? 17 : 32;

    // Phase A+prep: conv recurrence + all 5 weight transforms, ONE dispatch
    hipLaunchKernelGGL(k_prep, dim3(82176), dim3(256), 0, stream,
        cin, l, (l == 0) ? x_flat : OUT0, cw, cb, wq, wk, wo, wv,
        Hs_hi, Hs_lo, WT_hi, WTh_lo, WTc_hi, WTc_lo, WV_hi);

    // Phase B: QK + HO + Wvo in ONE 1280-block dispatch (5 CU rounds)
    hipLaunchKernelGGL(k_gemmB, dim3(1280), dim3(512), 0, stream,
        Hs_hi, Hs_lo, WT_hi, WTh_lo, WTc_hi, WTc_lo, WV_hi,
        QKOh, HOlo, Wvo_hi, Wvo_lo);

    // Scores, K-split x8, then softmax (re-arms barrier flags)
    hipLaunchKernelGGL(k_scores, dim3(1, 16, 8), dim3(256), 0, stream,
        QKOh, 12288L, 196608L, QKOh + 4096, 12288L, 196608L, Sp);
    hipLaunchKernelGGL(k_softmax, dim3(512), dim3(256), 0, stream, Sp, Wmx, flg);

    // Phase C: persistent kernel (1-hop barrier, overlapped pctx)
    hipLaunchKernelGGL(k_phaseC, dim3(256), dim3(512), 0, stream,
        Wvo_hi, Wvo_lo, Wmx, QKOh + 8192, HOlo,
        ring_h, (l == 0) ? OUT0 : dout, l, flg);
  }
}